// Round 1
// baseline (2923.847 us; speedup 1.0000x reference)
//
#include <hip/hip_runtime.h>
#include <math.h>

#define NN 100000
#define NE 1200000
#define NC 64

__device__ __forceinline__ float lane_bcast(float v, int l) {
    return __uint_as_float((unsigned)__builtin_amdgcn_readlane((int)__float_as_uint(v), l));
}

__global__ __launch_bounds__(256) void deg_kernel(const int* __restrict__ ei, int* __restrict__ deg) {
    int e = blockIdx.x * 256 + threadIdx.x;
    if (e < NE) atomicAdd(&deg[ei[e]], 1);
}

__global__ __launch_bounds__(1024) void scan_kernel(const int* __restrict__ deg,
                                                    float* __restrict__ dinv,
                                                    int* __restrict__ row_ptr) {
    __shared__ int sums[1024];
    const int CH = 98;  // 1024*98 >= 100000
    int t = threadIdx.x;
    int lo = t * CH, hi = lo + CH;
    if (hi > NN) hi = NN;
    int s = 0;
    for (int i = lo; i < hi; ++i) s += deg[i];
    sums[t] = s;
    __syncthreads();
    for (int off = 1; off < 1024; off <<= 1) {
        int v = (t >= off) ? sums[t - off] : 0;
        __syncthreads();
        sums[t] += v;
        __syncthreads();
    }
    int run = (t == 0) ? 0 : sums[t - 1];  // exclusive prefix
    for (int i = lo; i < hi; ++i) {
        int d = deg[i];
        row_ptr[i] = run;
        run += d;
        dinv[i] = (d > 0) ? rsqrtf((float)d) : 0.f;
    }
    if (t == 1023) row_ptr[NN] = run;  // == NE
}

__global__ __launch_bounds__(256) void fill_kernel(const int* __restrict__ ei,
                                                   const int* __restrict__ row_ptr,
                                                   int* __restrict__ cnt,
                                                   const float* __restrict__ dinv,
                                                   int2* __restrict__ csr) {
    int e = blockIdx.x * 256 + threadIdx.x;
    if (e >= NE) return;
    int r = ei[e];
    int c = ei[NE + e];
    int p = atomicAdd(&cnt[r], 1);
    csr[row_ptr[r] + p] = make_int2(c, (int)__float_as_uint(dinv[c]));
}

// Fused Chebyshev step:
//   FIRST: t2 = P(x);            out = x@W[0] + t2@W[1] + bias    (t0 == t1 == x)
//   else : t2 = 2*P(t1) - t0;    out += t2@W
// One wave handles 4 nodes; lane = channel.
template <bool FIRST>
__global__ __launch_bounds__(256) void cheb_kernel(
    const float* __restrict__ t0, const float* __restrict__ t1,
    float* __restrict__ t2, float* __restrict__ outp,
    const float* __restrict__ W, const float* __restrict__ bias,
    const int2* __restrict__ csr, const int* __restrict__ row_ptr,
    const float* __restrict__ dinv) {
    __shared__ float Wl[FIRST ? 8192 : 4096];
    const int nW = FIRST ? 8192 : 4096;
    for (int t = threadIdx.x; t < nW; t += 256) Wl[t] = W[t];
    __syncthreads();

    int lane = threadIdx.x & 63;
    int wid = threadIdx.x >> 6;
    int base = (blockIdx.x * 4 + wid) * 4;  // 4 nodes per wave; grid exact

    float t2v[4], x0v[4], o[4];
#pragma unroll
    for (int n = 0; n < 4; ++n) {
        int i = base + n;
        float di = dinv[i];
        int s = row_ptr[i];
        int e = row_ptr[i + 1];
        float acc = 0.f;
        for (int k = s; k < e; ++k) {
            int2 ce = csr[k];
            acc = fmaf(__uint_as_float((unsigned)ce.y), t1[ce.x * 64 + lane], acc);
        }
        float p = -di * acc;
        float x0 = t0[i * 64 + lane];
        x0v[n] = x0;
        t2v[n] = FIRST ? p : fmaf(2.f, p, -x0);
        t2[i * 64 + lane] = t2v[n];
        o[n] = FIRST ? bias[lane] : outp[i * 64 + lane];
    }

    if (FIRST) {
        float wreg[64];
#pragma unroll
        for (int c = 0; c < 64; ++c) wreg[c] = Wl[c * 64 + lane];  // W0 column for this lane
#pragma unroll
        for (int n = 0; n < 4; ++n)
#pragma unroll
            for (int c = 0; c < 64; ++c)
                o[n] = fmaf(lane_bcast(x0v[n], c), wreg[c], o[n]);
    }
    {
        float wreg[64];
#pragma unroll
        for (int c = 0; c < 64; ++c) wreg[c] = Wl[(FIRST ? 4096 : 0) + c * 64 + lane];  // Wk
#pragma unroll
        for (int n = 0; n < 4; ++n)
#pragma unroll
            for (int c = 0; c < 64; ++c)
                o[n] = fmaf(lane_bcast(t2v[n], c), wreg[c], o[n]);
    }
#pragma unroll
    for (int n = 0; n < 4; ++n) outp[(base + n) * 64 + lane] = o[n];
}

__global__ __launch_bounds__(256) void relu_kernel(float4* __restrict__ x, int n4) {
    int i = blockIdx.x * 256 + threadIdx.x;
    if (i < n4) {
        float4 v = x[i];
        v.x = fmaxf(v.x, 0.f); v.y = fmaxf(v.y, 0.f);
        v.z = fmaxf(v.z, 0.f); v.w = fmaxf(v.w, 0.f);
        x[i] = v;
    }
}

__global__ __launch_bounds__(256) void final_kernel(float4* __restrict__ out,
                                                    const float4* __restrict__ pos, int n4) {
    int i = blockIdx.x * 256 + threadIdx.x;
    if (i < n4) {
        float4 v = out[i];
        float4 p = pos[i];
        v.x = fmaxf(v.x, 0.f) + p.x; v.y = fmaxf(v.y, 0.f) + p.y;
        v.z = fmaxf(v.z, 0.f) + p.z; v.w = fmaxf(v.w, 0.f) + p.w;
        out[i] = v;
    }
}

extern "C" void kernel_launch(void* const* d_in, const int* in_sizes, int n_in,
                              void* d_out, int out_size, void* d_ws, size_t ws_size,
                              hipStream_t stream) {
    const float* pos = (const float*)d_in[0];
    const int* ei = (const int*)d_in[1];
    const float* W1 = (const float*)d_in[2];
    const float* b1 = (const float*)d_in[3];
    const float* W2 = (const float*)d_in[4];
    const float* b2 = (const float*)d_in[5];
    const float* W3 = (const float*)d_in[6];
    const float* b3 = (const float*)d_in[7];
    float* out = (float*)d_out;

    char* ws = (char*)d_ws;
    size_t off = 0;
    auto alloc = [&](size_t bytes) {
        void* p = ws + off;
        off += (bytes + 1023) & ~(size_t)1023;
        return p;
    };
    int* deg = (int*)alloc(NN * 4);
    float* dinv = (float*)alloc(NN * 4);
    int* row_ptr = (int*)alloc((NN + 1) * 4);
    int* cnt = (int*)alloc(NN * 4);
    int2* csr = (int2*)alloc((size_t)NE * 8);
    float* A = (float*)alloc((size_t)NN * NC * 4);
    float* B = (float*)alloc((size_t)NN * NC * 4);
    float* C = (float*)alloc((size_t)NN * NC * 4);

    hipMemsetAsync(deg, 0, NN * 4, stream);
    hipMemsetAsync(cnt, 0, NN * 4, stream);
    deg_kernel<<<(NE + 255) / 256, 256, 0, stream>>>(ei, deg);
    scan_kernel<<<1, 1024, 0, stream>>>(deg, dinv, row_ptr);
    fill_kernel<<<(NE + 255) / 256, 256, 0, stream>>>(ei, row_ptr, cnt, dinv, csr);

    const int G = NN / 16;   // 6250 blocks, 4 waves x 4 nodes each
    const int G4 = (NN * NC / 4) / 256;  // 6250

    // ---- layer 1: x = pos, out = d_out ----
    cheb_kernel<true><<<G, 256, 0, stream>>>(pos, pos, A, out, W1, b1, csr, row_ptr, dinv);
    cheb_kernel<false><<<G, 256, 0, stream>>>(pos, A, B, out, W1 + 2 * 4096, nullptr, csr, row_ptr, dinv);
    cheb_kernel<false><<<G, 256, 0, stream>>>(A, B, C, out, W1 + 3 * 4096, nullptr, csr, row_ptr, dinv);
    cheb_kernel<false><<<G, 256, 0, stream>>>(B, C, A, out, W1 + 4 * 4096, nullptr, csr, row_ptr, dinv);
    cheb_kernel<false><<<G, 256, 0, stream>>>(C, A, B, out, W1 + 5 * 4096, nullptr, csr, row_ptr, dinv);
    relu_kernel<<<G4, 256, 0, stream>>>((float4*)out, NN * NC / 4);

    // ---- layer 2: x = d_out, out = C ----
    cheb_kernel<true><<<G, 256, 0, stream>>>(out, out, A, C, W2, b2, csr, row_ptr, dinv);
    cheb_kernel<false><<<G, 256, 0, stream>>>(out, A, B, C, W2 + 2 * 4096, nullptr, csr, row_ptr, dinv);
    cheb_kernel<false><<<G, 256, 0, stream>>>(A, B, out, C, W2 + 3 * 4096, nullptr, csr, row_ptr, dinv);
    cheb_kernel<false><<<G, 256, 0, stream>>>(B, out, A, C, W2 + 4 * 4096, nullptr, csr, row_ptr, dinv);
    cheb_kernel<false><<<G, 256, 0, stream>>>(out, A, B, C, W2 + 5 * 4096, nullptr, csr, row_ptr, dinv);
    relu_kernel<<<G4, 256, 0, stream>>>((float4*)C, NN * NC / 4);

    // ---- layer 3: x = C, out = d_out ----
    cheb_kernel<true><<<G, 256, 0, stream>>>(C, C, A, out, W3, b3, csr, row_ptr, dinv);
    cheb_kernel<false><<<G, 256, 0, stream>>>(C, A, B, out, W3 + 2 * 4096, nullptr, csr, row_ptr, dinv);
    cheb_kernel<false><<<G, 256, 0, stream>>>(A, B, C, out, W3 + 3 * 4096, nullptr, csr, row_ptr, dinv);
    cheb_kernel<false><<<G, 256, 0, stream>>>(B, C, A, out, W3 + 4 * 4096, nullptr, csr, row_ptr, dinv);
    cheb_kernel<false><<<G, 256, 0, stream>>>(C, A, B, out, W3 + 5 * 4096, nullptr, csr, row_ptr, dinv);

    // ---- final: out = relu(out) + pos ----
    final_kernel<<<G4, 256, 0, stream>>>((float4*)out, (const float4*)pos, NN * NC / 4);
}

// Round 4
// 2106.780 us; speedup vs baseline: 1.3878x; 1.3878x over previous
//
#include <hip/hip_runtime.h>
#include <math.h>

#define NN 100000
#define NE 1200000
#define NC 64

__device__ __forceinline__ float lane_bcast(float v, int l) {
    return __uint_as_float((unsigned)__builtin_amdgcn_readlane((int)__float_as_uint(v), l));
}

__global__ __launch_bounds__(256) void deg_kernel(const int* __restrict__ ei, int* __restrict__ deg) {
    int e = blockIdx.x * 256 + threadIdx.x;
    if (e < NE) atomicAdd(&deg[ei[e]], 1);
}

__global__ __launch_bounds__(1024) void scan_kernel(const int* __restrict__ deg,
                                                    float* __restrict__ dinv,
                                                    int* __restrict__ row_ptr) {
    __shared__ int sums[1024];
    const int CH = 98;  // 1024*98 >= 100000
    int t = threadIdx.x;
    int lo = t * CH, hi = lo + CH;
    if (hi > NN) hi = NN;
    int s = 0;
    for (int i = lo; i < hi; ++i) s += deg[i];
    sums[t] = s;
    __syncthreads();
    for (int off = 1; off < 1024; off <<= 1) {
        int v = (t >= off) ? sums[t - off] : 0;
        __syncthreads();
        sums[t] += v;
        __syncthreads();
    }
    int run = (t == 0) ? 0 : sums[t - 1];  // exclusive prefix
    for (int i = lo; i < hi; ++i) {
        int d = deg[i];
        row_ptr[i] = run;
        run += d;
        dinv[i] = (d > 0) ? rsqrtf((float)d) : 0.f;
    }
    if (t == 1023) row_ptr[NN] = run;  // == NE
}

__global__ __launch_bounds__(256) void fill_kernel(const int* __restrict__ ei,
                                                   const int* __restrict__ row_ptr,
                                                   int* __restrict__ cnt,
                                                   const float* __restrict__ dinv,
                                                   int2* __restrict__ csr) {
    int e = blockIdx.x * 256 + threadIdx.x;
    if (e >= NE) return;
    int r = ei[e];
    int c = ei[NE + e];
    int p = atomicAdd(&cnt[r], 1);
    csr[row_ptr[r] + p] = make_int2(c, (int)__float_as_uint(dinv[c]));
}

// Fused Chebyshev step. One wave = 4 nodes, lane = channel.
//   FIRST: t2 = P(x);         out = bias + x@W0 + t2@W1   (t0 == t1 == x)
//   else : t2 = 2*P(t1)-t0;   out += t2@W0
// Gather strategy: one coalesced 8B/lane load pulls the node's whole edge
// list into a wave's registers (lane k = edge k); inner loop readlanes
// (col,w) so the t1 gathers are INDEPENDENT loads (no load->load chain).
template <bool FIRST>
__global__ __launch_bounds__(256) void cheb_kernel(
    const float* __restrict__ t0, const float* __restrict__ t1,
    float* __restrict__ t2, float* __restrict__ outp,
    const float* __restrict__ W0, const float* __restrict__ W1,
    const float* __restrict__ bias,
    const int2* __restrict__ csr, const int* __restrict__ row_ptr,
    const float* __restrict__ dinv) {
    __shared__ float Wl[4096];
    for (int t = threadIdx.x; t < 4096; t += 256) Wl[t] = W0[t];
    __syncthreads();

    int lane = threadIdx.x & 63;
    int wid = __builtin_amdgcn_readfirstlane(threadIdx.x >> 6);  // wave-uniform -> SGPR
    int base = (blockIdx.x * 4 + wid) * 4;

    int sN[4], dN[4];
    int2 ce[4];
#pragma unroll
    for (int n = 0; n < 4; ++n) {
        int i = base + n;
        sN[n] = row_ptr[i];
        dN[n] = row_ptr[i + 1] - sN[n];
        ce[n] = make_int2(0, 0);
        if (dN[n] > 0) ce[n] = csr[sN[n] + min(lane, dN[n] - 1)];
    }

    float acc[4];
#pragma unroll
    for (int n = 0; n < 4; ++n) {
        acc[n] = 0.f;
        int d = dN[n];
        int r0 = min(d, 64);
#pragma unroll 4
        for (int k = 0; k < r0; ++k) {
            int col = __builtin_amdgcn_readlane(ce[n].x, k);
            float w = __uint_as_float((unsigned)__builtin_amdgcn_readlane(ce[n].y, k));
            acc[n] = fmaf(w, t1[col * 64 + lane], acc[n]);
        }
        for (int b = 64; b < d; b += 64) {  // Poisson(12): essentially never
            int rem = min(d - b, 64);
            int2 c2 = csr[sN[n] + b + min(lane, rem - 1)];
            for (int k = 0; k < rem; ++k) {
                int col = __builtin_amdgcn_readlane(c2.x, k);
                float w = __uint_as_float((unsigned)__builtin_amdgcn_readlane(c2.y, k));
                acc[n] = fmaf(w, t1[col * 64 + lane], acc[n]);
            }
        }
    }

    float t2v[4], x0v[4], o[4];
#pragma unroll
    for (int n = 0; n < 4; ++n) {
        int i = base + n;
        float di = dinv[i];
        float p = -di * acc[n];
        float x0 = t0[i * 64 + lane];
        x0v[n] = x0;
        t2v[n] = FIRST ? p : fmaf(2.f, p, -x0);
        t2[i * 64 + lane] = t2v[n];
        o[n] = FIRST ? bias[lane] : outp[i * 64 + lane];
    }

    if (FIRST) {
        // o += x0 @ W0 (Wl holds W0)
#pragma unroll
        for (int c = 0; c < 64; ++c) {
            float wv = Wl[c * 64 + lane];
#pragma unroll
            for (int n = 0; n < 4; ++n)
                o[n] = fmaf(lane_bcast(x0v[n], c), wv, o[n]);
        }
        __syncthreads();
        for (int t = threadIdx.x; t < 4096; t += 256) Wl[t] = W1[t];
        __syncthreads();
    }

    // o += t2 @ W (Wl holds the step's weight)
#pragma unroll
    for (int c = 0; c < 64; ++c) {
        float wv = Wl[c * 64 + lane];
#pragma unroll
        for (int n = 0; n < 4; ++n)
            o[n] = fmaf(lane_bcast(t2v[n], c), wv, o[n]);
    }
#pragma unroll
    for (int n = 0; n < 4; ++n) outp[(base + n) * 64 + lane] = o[n];
}

__global__ __launch_bounds__(256) void relu_kernel(float4* __restrict__ x, int n4) {
    int i = blockIdx.x * 256 + threadIdx.x;
    if (i < n4) {
        float4 v = x[i];
        v.x = fmaxf(v.x, 0.f); v.y = fmaxf(v.y, 0.f);
        v.z = fmaxf(v.z, 0.f); v.w = fmaxf(v.w, 0.f);
        x[i] = v;
    }
}

__global__ __launch_bounds__(256) void final_kernel(float4* __restrict__ out,
                                                    const float4* __restrict__ pos, int n4) {
    int i = blockIdx.x * 256 + threadIdx.x;
    if (i < n4) {
        float4 v = out[i];
        float4 p = pos[i];
        v.x = fmaxf(v.x, 0.f) + p.x; v.y = fmaxf(v.y, 0.f) + p.y;
        v.z = fmaxf(v.z, 0.f) + p.z; v.w = fmaxf(v.w, 0.f) + p.w;
        out[i] = v;
    }
}

extern "C" void kernel_launch(void* const* d_in, const int* in_sizes, int n_in,
                              void* d_out, int out_size, void* d_ws, size_t ws_size,
                              hipStream_t stream) {
    const float* pos = (const float*)d_in[0];
    const int* ei = (const int*)d_in[1];
    const float* W1 = (const float*)d_in[2];
    const float* b1 = (const float*)d_in[3];
    const float* W2 = (const float*)d_in[4];
    const float* b2 = (const float*)d_in[5];
    const float* W3 = (const float*)d_in[6];
    const float* b3 = (const float*)d_in[7];
    float* out = (float*)d_out;

    char* ws = (char*)d_ws;
    size_t off = 0;
    auto alloc = [&](size_t bytes) {
        void* p = ws + off;
        off += (bytes + 1023) & ~(size_t)1023;
        return p;
    };
    int* deg = (int*)alloc(NN * 4);
    float* dinv = (float*)alloc(NN * 4);
    int* row_ptr = (int*)alloc((NN + 1) * 4);
    int* cnt = (int*)alloc(NN * 4);
    int2* csr = (int2*)alloc((size_t)NE * 8);
    float* A = (float*)alloc((size_t)NN * NC * 4);
    float* B = (float*)alloc((size_t)NN * NC * 4);
    float* C = (float*)alloc((size_t)NN * NC * 4);

    hipMemsetAsync(deg, 0, NN * 4, stream);
    hipMemsetAsync(cnt, 0, NN * 4, stream);
    deg_kernel<<<(NE + 255) / 256, 256, 0, stream>>>(ei, deg);
    scan_kernel<<<1, 1024, 0, stream>>>(deg, dinv, row_ptr);
    fill_kernel<<<(NE + 255) / 256, 256, 0, stream>>>(ei, row_ptr, cnt, dinv, csr);

    const int G = NN / 16;               // 6250 blocks, 4 waves x 4 nodes
    const int G4 = (NN * NC / 4) / 256;  // 6250

    // ---- layer 1: x = pos, out = d_out ----
    cheb_kernel<true><<<G, 256, 0, stream>>>(pos, pos, A, out, W1, W1 + 4096, b1, csr, row_ptr, dinv);
    cheb_kernel<false><<<G, 256, 0, stream>>>(pos, A, B, out, W1 + 2 * 4096, nullptr, nullptr, csr, row_ptr, dinv);
    cheb_kernel<false><<<G, 256, 0, stream>>>(A, B, C, out, W1 + 3 * 4096, nullptr, nullptr, csr, row_ptr, dinv);
    cheb_kernel<false><<<G, 256, 0, stream>>>(B, C, A, out, W1 + 4 * 4096, nullptr, nullptr, csr, row_ptr, dinv);
    cheb_kernel<false><<<G, 256, 0, stream>>>(C, A, B, out, W1 + 5 * 4096, nullptr, nullptr, csr, row_ptr, dinv);
    relu_kernel<<<G4, 256, 0, stream>>>((float4*)out, NN * NC / 4);

    // ---- layer 2: x = d_out, out = C ----
    cheb_kernel<true><<<G, 256, 0, stream>>>(out, out, A, C, W2, W2 + 4096, b2, csr, row_ptr, dinv);
    cheb_kernel<false><<<G, 256, 0, stream>>>(out, A, B, C, W2 + 2 * 4096, nullptr, nullptr, csr, row_ptr, dinv);
    cheb_kernel<false><<<G, 256, 0, stream>>>(A, B, out, C, W2 + 3 * 4096, nullptr, nullptr, csr, row_ptr, dinv);
    cheb_kernel<false><<<G, 256, 0, stream>>>(B, out, A, C, W2 + 4 * 4096, nullptr, nullptr, csr, row_ptr, dinv);
    cheb_kernel<false><<<G, 256, 0, stream>>>(out, A, B, C, W2 + 5 * 4096, nullptr, nullptr, csr, row_ptr, dinv);
    relu_kernel<<<G4, 256, 0, stream>>>((float4*)C, NN * NC / 4);

    // ---- layer 3: x = C, out = d_out ----
    cheb_kernel<true><<<G, 256, 0, stream>>>(C, C, A, out, W3, W3 + 4096, b3, csr, row_ptr, dinv);
    cheb_kernel<false><<<G, 256, 0, stream>>>(C, A, B, out, W3 + 2 * 4096, nullptr, nullptr, csr, row_ptr, dinv);
    cheb_kernel<false><<<G, 256, 0, stream>>>(A, B, C, out, W3 + 3 * 4096, nullptr, nullptr, csr, row_ptr, dinv);
    cheb_kernel<false><<<G, 256, 0, stream>>>(B, C, A, out, W3 + 4 * 4096, nullptr, nullptr, csr, row_ptr, dinv);
    cheb_kernel<false><<<G, 256, 0, stream>>>(C, A, B, out, W3 + 5 * 4096, nullptr, nullptr, csr, row_ptr, dinv);

    // ---- final: out = relu(out) + pos ----
    final_kernel<<<G4, 256, 0, stream>>>((float4*)out, (const float4*)pos, NN * NC / 4);
}

// Round 7
// 1869.886 us; speedup vs baseline: 1.5637x; 1.1267x over previous
//
#include <hip/hip_runtime.h>
#include <math.h>

#define NN 100000
#define NE 1200000
#define NC 64
#define NB 391  // ceil(NN/256)

__device__ __forceinline__ float lane_bcast(float v, int l) {
    return __uint_as_float((unsigned)__builtin_amdgcn_readlane((int)__float_as_uint(v), l));
}

__global__ __launch_bounds__(256) void deg_kernel(const int* __restrict__ ei, int* __restrict__ deg) {
    int e = blockIdx.x * 256 + threadIdx.x;
    if (e < NE) atomicAdd(&deg[ei[e]], 1);
}

// --- device-wide exclusive scan of deg[] in 3 small kernels ---
__global__ __launch_bounds__(256) void scan1_kernel(const int* __restrict__ deg,
                                                    int* __restrict__ tmp,
                                                    int* __restrict__ bsum) {
    __shared__ int s[256];
    int i = blockIdx.x * 256 + threadIdx.x;
    int v = (i < NN) ? deg[i] : 0;
    s[threadIdx.x] = v;
    __syncthreads();
    for (int off = 1; off < 256; off <<= 1) {
        int t = (threadIdx.x >= off) ? s[threadIdx.x - off] : 0;
        __syncthreads();
        s[threadIdx.x] += t;
        __syncthreads();
    }
    if (i < NN) tmp[i] = s[threadIdx.x];  // inclusive within block
    if (threadIdx.x == 255) bsum[blockIdx.x] = s[255];
}

__global__ __launch_bounds__(512) void scan2_kernel(const int* __restrict__ bsum,
                                                    int* __restrict__ boff) {
    __shared__ int s[512];
    int t = threadIdx.x;
    int v = (t < NB) ? bsum[t] : 0;
    s[t] = v;
    __syncthreads();
    for (int off = 1; off < 512; off <<= 1) {
        int u = (t >= off) ? s[t - off] : 0;
        __syncthreads();
        s[t] += u;
        __syncthreads();
    }
    if (t < NB) boff[t] = s[t] - v;  // exclusive
}

__global__ __launch_bounds__(256) void scan3_kernel(const int* __restrict__ deg,
                                                    const int* __restrict__ tmp,
                                                    const int* __restrict__ boff,
                                                    int* __restrict__ row_ptr,
                                                    float* __restrict__ dinv) {
    int i = blockIdx.x * 256 + threadIdx.x;
    if (i >= NN) return;
    int d = deg[i];
    int start = tmp[i] - d + boff[blockIdx.x];
    row_ptr[i] = start;
    dinv[i] = (d > 0) ? rsqrtf((float)d) : 0.f;
    if (i == NN - 1) row_ptr[NN] = start + d;
}

__global__ __launch_bounds__(256) void fill_kernel(const int* __restrict__ ei,
                                                   const int* __restrict__ row_ptr,
                                                   int* __restrict__ cnt,
                                                   const float* __restrict__ dinv,
                                                   int2* __restrict__ csr) {
    int e = blockIdx.x * 256 + threadIdx.x;
    if (e >= NE) return;
    int r = ei[e];
    int c = ei[NE + e];
    int p = atomicAdd(&cnt[r], 1);
    csr[row_ptr[r] + p] = make_int2(c, (int)__float_as_uint(dinv[c]));
}

// Fused Chebyshev step. One wave = 4 nodes, lane = channel.
//   FIRST: t2 = P(x);         out = bias + x@W0 + t2@W1   (t0 == t1 == x)
//   else : t2 = 2*P(t1)-t0;   out += t2@W0
// Gather strategy: one coalesced 8B/lane load pulls the node's whole edge
// list into a wave's registers (lane k = edge k); inner loop readlanes
// (col,w) so the t1 gathers are INDEPENDENT loads (no load->load chain).
template <bool FIRST>
__global__ __launch_bounds__(256) void cheb_kernel(
    const float* __restrict__ t0, const float* __restrict__ t1,
    float* __restrict__ t2, float* __restrict__ outp,
    const float* __restrict__ W0, const float* __restrict__ W1,
    const float* __restrict__ bias,
    const int2* __restrict__ csr, const int* __restrict__ row_ptr,
    const float* __restrict__ dinv) {
    __shared__ float Wl[4096];
    for (int t = threadIdx.x; t < 4096; t += 256) Wl[t] = W0[t];
    __syncthreads();

    int lane = threadIdx.x & 63;
    int wid = __builtin_amdgcn_readfirstlane(threadIdx.x >> 6);  // wave-uniform -> SGPR
    int base = (blockIdx.x * 4 + wid) * 4;

    int sN[4], dN[4];
    int2 ce[4];
#pragma unroll
    for (int n = 0; n < 4; ++n) {
        int i = base + n;
        sN[n] = row_ptr[i];
        dN[n] = row_ptr[i + 1] - sN[n];
        ce[n] = make_int2(0, 0);
        if (dN[n] > 0) ce[n] = csr[sN[n] + min(lane, dN[n] - 1)];
    }

    float acc[4];
#pragma unroll
    for (int n = 0; n < 4; ++n) {
        acc[n] = 0.f;
        int d = dN[n];
        int r0 = min(d, 64);
#pragma unroll 4
        for (int k = 0; k < r0; ++k) {
            int col = __builtin_amdgcn_readlane(ce[n].x, k);
            float w = __uint_as_float((unsigned)__builtin_amdgcn_readlane(ce[n].y, k));
            acc[n] = fmaf(w, t1[col * 64 + lane], acc[n]);
        }
        for (int b = 64; b < d; b += 64) {  // Poisson(12): essentially never
            int rem = min(d - b, 64);
            int2 c2 = csr[sN[n] + b + min(lane, rem - 1)];
            for (int k = 0; k < rem; ++k) {
                int col = __builtin_amdgcn_readlane(c2.x, k);
                float w = __uint_as_float((unsigned)__builtin_amdgcn_readlane(c2.y, k));
                acc[n] = fmaf(w, t1[col * 64 + lane], acc[n]);
            }
        }
    }

    float t2v[4], x0v[4], o[4];
#pragma unroll
    for (int n = 0; n < 4; ++n) {
        int i = base + n;
        float di = dinv[i];
        float p = -di * acc[n];
        float x0 = t0[i * 64 + lane];
        x0v[n] = x0;
        t2v[n] = FIRST ? p : fmaf(2.f, p, -x0);
        t2[i * 64 + lane] = t2v[n];
        o[n] = FIRST ? bias[lane] : outp[i * 64 + lane];
    }

    if (FIRST) {
        // o += x0 @ W0 (Wl holds W0)
#pragma unroll
        for (int c = 0; c < 64; ++c) {
            float wv = Wl[c * 64 + lane];
#pragma unroll
            for (int n = 0; n < 4; ++n)
                o[n] = fmaf(lane_bcast(x0v[n], c), wv, o[n]);
        }
        __syncthreads();
        for (int t = threadIdx.x; t < 4096; t += 256) Wl[t] = W1[t];
        __syncthreads();
    }

    // o += t2 @ W (Wl holds the step's weight)
#pragma unroll
    for (int c = 0; c < 64; ++c) {
        float wv = Wl[c * 64 + lane];
#pragma unroll
        for (int n = 0; n < 4; ++n)
            o[n] = fmaf(lane_bcast(t2v[n], c), wv, o[n]);
    }
#pragma unroll
    for (int n = 0; n < 4; ++n) outp[(base + n) * 64 + lane] = o[n];
}

__global__ __launch_bounds__(256) void relu_kernel(float4* __restrict__ x, int n4) {
    int i = blockIdx.x * 256 + threadIdx.x;
    if (i < n4) {
        float4 v = x[i];
        v.x = fmaxf(v.x, 0.f); v.y = fmaxf(v.y, 0.f);
        v.z = fmaxf(v.z, 0.f); v.w = fmaxf(v.w, 0.f);
        x[i] = v;
    }
}

__global__ __launch_bounds__(256) void final_kernel(float4* __restrict__ out,
                                                    const float4* __restrict__ pos, int n4) {
    int i = blockIdx.x * 256 + threadIdx.x;
    if (i < n4) {
        float4 v = out[i];
        float4 p = pos[i];
        v.x = fmaxf(v.x, 0.f) + p.x; v.y = fmaxf(v.y, 0.f) + p.y;
        v.z = fmaxf(v.z, 0.f) + p.z; v.w = fmaxf(v.w, 0.f) + p.w;
        out[i] = v;
    }
}

extern "C" void kernel_launch(void* const* d_in, const int* in_sizes, int n_in,
                              void* d_out, int out_size, void* d_ws, size_t ws_size,
                              hipStream_t stream) {
    const float* pos = (const float*)d_in[0];
    const int* ei = (const int*)d_in[1];
    const float* W1 = (const float*)d_in[2];
    const float* b1 = (const float*)d_in[3];
    const float* W2 = (const float*)d_in[4];
    const float* b2 = (const float*)d_in[5];
    const float* W3 = (const float*)d_in[6];
    const float* b3 = (const float*)d_in[7];
    float* out = (float*)d_out;

    char* ws = (char*)d_ws;
    size_t off = 0;
    auto alloc = [&](size_t bytes) {
        void* p = ws + off;
        off += (bytes + 1023) & ~(size_t)1023;
        return p;
    };
    int* deg = (int*)alloc(NN * 4);
    float* dinv = (float*)alloc(NN * 4);
    int* row_ptr = (int*)alloc((NN + 1) * 4);
    int* cnt = (int*)alloc(NN * 4);
    int* tmp = (int*)alloc(NN * 4);
    int* bsum = (int*)alloc(NB * 4);
    int* boff = (int*)alloc(NB * 4);
    int2* csr = (int2*)alloc((size_t)NE * 8);
    float* A = (float*)alloc((size_t)NN * NC * 4);
    float* B = (float*)alloc((size_t)NN * NC * 4);
    float* C = (float*)alloc((size_t)NN * NC * 4);

    hipMemsetAsync(deg, 0, NN * 4, stream);
    hipMemsetAsync(cnt, 0, NN * 4, stream);
    deg_kernel<<<(NE + 255) / 256, 256, 0, stream>>>(ei, deg);
    scan1_kernel<<<NB, 256, 0, stream>>>(deg, tmp, bsum);
    scan2_kernel<<<1, 512, 0, stream>>>(bsum, boff);
    scan3_kernel<<<NB, 256, 0, stream>>>(deg, tmp, boff, row_ptr, dinv);
    fill_kernel<<<(NE + 255) / 256, 256, 0, stream>>>(ei, row_ptr, cnt, dinv, csr);

    const int G = NN / 16;               // 6250 blocks, 4 waves x 4 nodes
    const int G4 = (NN * NC / 4) / 256;  // 6250

    // ---- layer 1: x = pos, out = d_out ----
    cheb_kernel<true><<<G, 256, 0, stream>>>(pos, pos, A, out, W1, W1 + 4096, b1, csr, row_ptr, dinv);
    cheb_kernel<false><<<G, 256, 0, stream>>>(pos, A, B, out, W1 + 2 * 4096, nullptr, nullptr, csr, row_ptr, dinv);
    cheb_kernel<false><<<G, 256, 0, stream>>>(A, B, C, out, W1 + 3 * 4096, nullptr, nullptr, csr, row_ptr, dinv);
    cheb_kernel<false><<<G, 256, 0, stream>>>(B, C, A, out, W1 + 4 * 4096, nullptr, nullptr, csr, row_ptr, dinv);
    cheb_kernel<false><<<G, 256, 0, stream>>>(C, A, B, out, W1 + 5 * 4096, nullptr, nullptr, csr, row_ptr, dinv);
    relu_kernel<<<G4, 256, 0, stream>>>((float4*)out, NN * NC / 4);

    // ---- layer 2: x = d_out, out = C ----
    cheb_kernel<true><<<G, 256, 0, stream>>>(out, out, A, C, W2, W2 + 4096, b2, csr, row_ptr, dinv);
    cheb_kernel<false><<<G, 256, 0, stream>>>(out, A, B, C, W2 + 2 * 4096, nullptr, nullptr, csr, row_ptr, dinv);
    cheb_kernel<false><<<G, 256, 0, stream>>>(A, B, out, C, W2 + 3 * 4096, nullptr, nullptr, csr, row_ptr, dinv);
    cheb_kernel<false><<<G, 256, 0, stream>>>(B, out, A, C, W2 + 4 * 4096, nullptr, nullptr, csr, row_ptr, dinv);
    cheb_kernel<false><<<G, 256, 0, stream>>>(out, A, B, C, W2 + 5 * 4096, nullptr, nullptr, csr, row_ptr, dinv);
    relu_kernel<<<G4, 256, 0, stream>>>((float4*)C, NN * NC / 4);

    // ---- layer 3: x = C, out = d_out ----
    cheb_kernel<true><<<G, 256, 0, stream>>>(C, C, A, out, W3, W3 + 4096, b3, csr, row_ptr, dinv);
    cheb_kernel<false><<<G, 256, 0, stream>>>(C, A, B, out, W3 + 2 * 4096, nullptr, nullptr, csr, row_ptr, dinv);
    cheb_kernel<false><<<G, 256, 0, stream>>>(A, B, C, out, W3 + 3 * 4096, nullptr, nullptr, csr, row_ptr, dinv);
    cheb_kernel<false><<<G, 256, 0, stream>>>(B, C, A, out, W3 + 4 * 4096, nullptr, nullptr, csr, row_ptr, dinv);
    cheb_kernel<false><<<G, 256, 0, stream>>>(C, A, B, out, W3 + 5 * 4096, nullptr, nullptr, csr, row_ptr, dinv);

    // ---- final: out = relu(out) + pos ----
    final_kernel<<<G4, 256, 0, stream>>>((float4*)out, (const float4*)pos, NN * NC / 4);
}

// Round 8
// 1826.706 us; speedup vs baseline: 1.6006x; 1.0236x over previous
//
#include <hip/hip_runtime.h>
#include <hip/hip_bf16.h>
#include <math.h>

#define NN 100000
#define NE 1200000
#define NC 64
#define NB 391  // ceil(NN/256)

typedef unsigned short u16;

__device__ __forceinline__ float lane_bcast(float v, int l) {
    return __uint_as_float((unsigned)__builtin_amdgcn_readlane((int)__float_as_uint(v), l));
}
__device__ __forceinline__ float bf2f(u16 u) {
    return __uint_as_float(((unsigned)u) << 16);
}
__device__ __forceinline__ u16 f2bf(float f) {
    __hip_bfloat16 h = __float2bfloat16(f);  // RTN
    return *reinterpret_cast<u16*>(&h);
}

__global__ __launch_bounds__(256) void deg_kernel(const int* __restrict__ ei, int* __restrict__ deg) {
    int e = blockIdx.x * 256 + threadIdx.x;
    if (e < NE) atomicAdd(&deg[ei[e]], 1);
}

// --- device-wide exclusive scan of deg[] ---
__global__ __launch_bounds__(256) void scan1_kernel(const int* __restrict__ deg,
                                                    int* __restrict__ tmp,
                                                    int* __restrict__ bsum) {
    __shared__ int s[256];
    int i = blockIdx.x * 256 + threadIdx.x;
    int v = (i < NN) ? deg[i] : 0;
    s[threadIdx.x] = v;
    __syncthreads();
    for (int off = 1; off < 256; off <<= 1) {
        int t = (threadIdx.x >= off) ? s[threadIdx.x - off] : 0;
        __syncthreads();
        s[threadIdx.x] += t;
        __syncthreads();
    }
    if (i < NN) tmp[i] = s[threadIdx.x];
    if (threadIdx.x == 255) bsum[blockIdx.x] = s[255];
}

__global__ __launch_bounds__(512) void scan2_kernel(const int* __restrict__ bsum,
                                                    int* __restrict__ boff) {
    __shared__ int s[512];
    int t = threadIdx.x;
    int v = (t < NB) ? bsum[t] : 0;
    s[t] = v;
    __syncthreads();
    for (int off = 1; off < 512; off <<= 1) {
        int u = (t >= off) ? s[t - off] : 0;
        __syncthreads();
        s[t] += u;
        __syncthreads();
    }
    if (t < NB) boff[t] = s[t] - v;
}

__global__ __launch_bounds__(256) void scan3_kernel(const int* __restrict__ deg,
                                                    const int* __restrict__ tmp,
                                                    const int* __restrict__ boff,
                                                    int* __restrict__ row_ptr,
                                                    float* __restrict__ dinv) {
    int i = blockIdx.x * 256 + threadIdx.x;
    if (i >= NN) return;
    int d = deg[i];
    int start = tmp[i] - d + boff[blockIdx.x];
    row_ptr[i] = start;
    dinv[i] = (d > 0) ? rsqrtf((float)d) : 0.f;
    if (i == NN - 1) row_ptr[NN] = start + d;
}

__global__ __launch_bounds__(256) void fill_kernel(const int* __restrict__ ei,
                                                   const int* __restrict__ row_ptr,
                                                   int* __restrict__ cnt,
                                                   const float* __restrict__ dinv,
                                                   int2* __restrict__ csr) {
    int e = blockIdx.x * 256 + threadIdx.x;
    if (e >= NE) return;
    int r = ei[e];
    int c = ei[NE + e];
    int p = atomicAdd(&cnt[r], 1);
    csr[row_ptr[r] + p] = make_int2(c, (int)__float_as_uint(dinv[c]));
}

// Fused Chebyshev step, bf16 T-state. One wave = 4 nodes, lane = channel.
//   FIRST: t2 = P(x);         out = bias + x@W0 + t2@W1   (t0 == t1 == x)
//   else : t2 = 2*P(t1)-t0;   out += t2@W0
template <bool FIRST>
__global__ __launch_bounds__(256) void cheb_kernel(
    const u16* __restrict__ t0, const u16* __restrict__ t1,
    u16* __restrict__ t2, float* __restrict__ outp,
    const float* __restrict__ W0, const float* __restrict__ W1,
    const float* __restrict__ bias,
    const int2* __restrict__ csr, const int* __restrict__ row_ptr,
    const float* __restrict__ dinv) {
    __shared__ float Wl[4096];
    for (int t = threadIdx.x; t < 4096; t += 256) Wl[t] = W0[t];
    __syncthreads();

    int lane = threadIdx.x & 63;
    int wid = __builtin_amdgcn_readfirstlane(threadIdx.x >> 6);
    int base = (blockIdx.x * 4 + wid) * 4;

    int sN[4], dN[4];
    int2 ce[4];
#pragma unroll
    for (int n = 0; n < 4; ++n) {
        int i = base + n;
        sN[n] = row_ptr[i];
        dN[n] = row_ptr[i + 1] - sN[n];
        ce[n] = make_int2(0, 0);
        if (dN[n] > 0) ce[n] = csr[sN[n] + min(lane, dN[n] - 1)];
    }

    float acc[4];
#pragma unroll
    for (int n = 0; n < 4; ++n) {
        acc[n] = 0.f;
        int d = dN[n];
        int r0 = min(d, 64);
#pragma unroll 8
        for (int k = 0; k < r0; ++k) {
            int col = __builtin_amdgcn_readlane(ce[n].x, k);
            float w = __uint_as_float((unsigned)__builtin_amdgcn_readlane(ce[n].y, k));
            acc[n] = fmaf(w, bf2f(t1[col * 64 + lane]), acc[n]);
        }
        for (int b = 64; b < d; b += 64) {  // Poisson(12): essentially never
            int rem = min(d - b, 64);
            int2 c2 = csr[sN[n] + b + min(lane, rem - 1)];
            for (int k = 0; k < rem; ++k) {
                int col = __builtin_amdgcn_readlane(c2.x, k);
                float w = __uint_as_float((unsigned)__builtin_amdgcn_readlane(c2.y, k));
                acc[n] = fmaf(w, bf2f(t1[col * 64 + lane]), acc[n]);
            }
        }
    }

    float t2v[4], x0v[4], o[4];
#pragma unroll
    for (int n = 0; n < 4; ++n) {
        int i = base + n;
        float di = dinv[i];
        float p = -di * acc[n];
        float x0 = bf2f(t0[i * 64 + lane]);
        x0v[n] = x0;
        t2v[n] = FIRST ? p : fmaf(2.f, p, -x0);
        t2[i * 64 + lane] = f2bf(t2v[n]);
        o[n] = FIRST ? bias[lane] : outp[i * 64 + lane];
    }

    if (FIRST) {
        // o += x0 @ W0 (Wl holds W0)
#pragma unroll
        for (int c = 0; c < 64; ++c) {
            float wv = Wl[c * 64 + lane];
#pragma unroll
            for (int n = 0; n < 4; ++n)
                o[n] = fmaf(lane_bcast(x0v[n], c), wv, o[n]);
        }
        __syncthreads();
        for (int t = threadIdx.x; t < 4096; t += 256) Wl[t] = W1[t];
        __syncthreads();
    }

    // o += t2 @ W
#pragma unroll
    for (int c = 0; c < 64; ++c) {
        float wv = Wl[c * 64 + lane];
#pragma unroll
        for (int n = 0; n < 4; ++n)
            o[n] = fmaf(lane_bcast(t2v[n], c), wv, o[n]);
    }
#pragma unroll
    for (int n = 0; n < 4; ++n) outp[(base + n) * 64 + lane] = o[n];
}

__global__ __launch_bounds__(256) void cvt_kernel(const float4* __restrict__ in,
                                                  ushort4* __restrict__ outb, int n4) {
    int i = blockIdx.x * 256 + threadIdx.x;
    if (i < n4) {
        float4 v = in[i];
        ushort4 u;
        u.x = f2bf(v.x); u.y = f2bf(v.y); u.z = f2bf(v.z); u.w = f2bf(v.w);
        outb[i] = u;
    }
}

// h = relu(O) stored ONLY as bf16 (next layer never needs the f32 copy)
__global__ __launch_bounds__(256) void relu_cvt_kernel(const float4* __restrict__ in,
                                                       ushort4* __restrict__ outb, int n4) {
    int i = blockIdx.x * 256 + threadIdx.x;
    if (i < n4) {
        float4 v = in[i];
        ushort4 u;
        u.x = f2bf(fmaxf(v.x, 0.f)); u.y = f2bf(fmaxf(v.y, 0.f));
        u.z = f2bf(fmaxf(v.z, 0.f)); u.w = f2bf(fmaxf(v.w, 0.f));
        outb[i] = u;
    }
}

__global__ __launch_bounds__(256) void final_kernel(float4* __restrict__ out,
                                                    const float4* __restrict__ pos, int n4) {
    int i = blockIdx.x * 256 + threadIdx.x;
    if (i < n4) {
        float4 v = out[i];
        float4 p = pos[i];
        v.x = fmaxf(v.x, 0.f) + p.x; v.y = fmaxf(v.y, 0.f) + p.y;
        v.z = fmaxf(v.z, 0.f) + p.z; v.w = fmaxf(v.w, 0.f) + p.w;
        out[i] = v;
    }
}

extern "C" void kernel_launch(void* const* d_in, const int* in_sizes, int n_in,
                              void* d_out, int out_size, void* d_ws, size_t ws_size,
                              hipStream_t stream) {
    const float* pos = (const float*)d_in[0];
    const int* ei = (const int*)d_in[1];
    const float* W1 = (const float*)d_in[2];
    const float* b1 = (const float*)d_in[3];
    const float* W2 = (const float*)d_in[4];
    const float* b2 = (const float*)d_in[5];
    const float* W3 = (const float*)d_in[6];
    const float* b3 = (const float*)d_in[7];
    float* out = (float*)d_out;

    char* ws = (char*)d_ws;
    size_t off = 0;
    auto alloc = [&](size_t bytes) {
        void* p = ws + off;
        off += (bytes + 1023) & ~(size_t)1023;
        return p;
    };
    int* deg = (int*)alloc(NN * 4);
    float* dinv = (float*)alloc(NN * 4);
    int* row_ptr = (int*)alloc((NN + 1) * 4);
    int* cnt = (int*)alloc(NN * 4);
    int* tmp = (int*)alloc(NN * 4);
    int* bsum = (int*)alloc(NB * 4);
    int* boff = (int*)alloc(NB * 4);
    int2* csr = (int2*)alloc((size_t)NE * 8);
    u16* X = (u16*)alloc((size_t)NN * NC * 2);
    u16* A = (u16*)alloc((size_t)NN * NC * 2);
    u16* B = (u16*)alloc((size_t)NN * NC * 2);
    u16* C = (u16*)alloc((size_t)NN * NC * 2);
    float* O = (float*)alloc((size_t)NN * NC * 4);

    hipMemsetAsync(deg, 0, NN * 4, stream);
    hipMemsetAsync(cnt, 0, NN * 4, stream);
    deg_kernel<<<(NE + 255) / 256, 256, 0, stream>>>(ei, deg);
    scan1_kernel<<<NB, 256, 0, stream>>>(deg, tmp, bsum);
    scan2_kernel<<<1, 512, 0, stream>>>(bsum, boff);
    scan3_kernel<<<NB, 256, 0, stream>>>(deg, tmp, boff, row_ptr, dinv);
    fill_kernel<<<(NE + 255) / 256, 256, 0, stream>>>(ei, row_ptr, cnt, dinv, csr);

    const int G = NN / 16;               // 6250 blocks, 4 waves x 4 nodes
    const int G4 = (NN * NC / 4) / 256;  // 6250

    cvt_kernel<<<G4, 256, 0, stream>>>((const float4*)pos, (ushort4*)X, NN * NC / 4);

    // ---- layer 1: x = X(bf16 pos), out accum = O ----
    cheb_kernel<true><<<G, 256, 0, stream>>>(X, X, A, O, W1, W1 + 4096, b1, csr, row_ptr, dinv);
    cheb_kernel<false><<<G, 256, 0, stream>>>(X, A, B, O, W1 + 2 * 4096, nullptr, nullptr, csr, row_ptr, dinv);
    cheb_kernel<false><<<G, 256, 0, stream>>>(A, B, C, O, W1 + 3 * 4096, nullptr, nullptr, csr, row_ptr, dinv);
    cheb_kernel<false><<<G, 256, 0, stream>>>(B, C, A, O, W1 + 4 * 4096, nullptr, nullptr, csr, row_ptr, dinv);
    cheb_kernel<false><<<G, 256, 0, stream>>>(C, A, B, O, W1 + 5 * 4096, nullptr, nullptr, csr, row_ptr, dinv);
    relu_cvt_kernel<<<G4, 256, 0, stream>>>((const float4*)O, (ushort4*)X, NN * NC / 4);

    // ---- layer 2 ----
    cheb_kernel<true><<<G, 256, 0, stream>>>(X, X, A, O, W2, W2 + 4096, b2, csr, row_ptr, dinv);
    cheb_kernel<false><<<G, 256, 0, stream>>>(X, A, B, O, W2 + 2 * 4096, nullptr, nullptr, csr, row_ptr, dinv);
    cheb_kernel<false><<<G, 256, 0, stream>>>(A, B, C, O, W2 + 3 * 4096, nullptr, nullptr, csr, row_ptr, dinv);
    cheb_kernel<false><<<G, 256, 0, stream>>>(B, C, A, O, W2 + 4 * 4096, nullptr, nullptr, csr, row_ptr, dinv);
    cheb_kernel<false><<<G, 256, 0, stream>>>(C, A, B, O, W2 + 5 * 4096, nullptr, nullptr, csr, row_ptr, dinv);
    relu_cvt_kernel<<<G4, 256, 0, stream>>>((const float4*)O, (ushort4*)X, NN * NC / 4);

    // ---- layer 3: out accum = d_out ----
    cheb_kernel<true><<<G, 256, 0, stream>>>(X, X, A, out, W3, W3 + 4096, b3, csr, row_ptr, dinv);
    cheb_kernel<false><<<G, 256, 0, stream>>>(X, A, B, out, W3 + 2 * 4096, nullptr, nullptr, csr, row_ptr, dinv);
    cheb_kernel<false><<<G, 256, 0, stream>>>(A, B, C, out, W3 + 3 * 4096, nullptr, nullptr, csr, row_ptr, dinv);
    cheb_kernel<false><<<G, 256, 0, stream>>>(B, C, A, out, W3 + 4 * 4096, nullptr, nullptr, csr, row_ptr, dinv);
    cheb_kernel<false><<<G, 256, 0, stream>>>(C, A, B, out, W3 + 5 * 4096, nullptr, nullptr, csr, row_ptr, dinv);

    // ---- final: out = relu(out) + pos ----
    final_kernel<<<G4, 256, 0, stream>>>((float4*)out, (const float4*)pos, NN * NC / 4);
}

// Round 9
// 1386.200 us; speedup vs baseline: 2.1093x; 1.3178x over previous
//
#include <hip/hip_runtime.h>
#include <hip/hip_bf16.h>
#include <math.h>

#define NN 100000
#define NE 1200000
#define NC 64
#define NB 391     // ceil(NN/256)
#define NTILE 6250 // NN/16

typedef unsigned short u16;
typedef __attribute__((ext_vector_type(8))) short short8;
typedef __attribute__((ext_vector_type(4))) float f32x4;

__device__ __forceinline__ float bf2f(u16 u) {
    return __uint_as_float(((unsigned)u) << 16);
}
__device__ __forceinline__ u16 f2bf(float f) {
    __hip_bfloat16 h = __float2bfloat16(f);  // RTN
    return *reinterpret_cast<u16*>(&h);
}

__global__ __launch_bounds__(256) void deg_kernel(const int* __restrict__ ei, int* __restrict__ deg) {
    int e = blockIdx.x * 256 + threadIdx.x;
    if (e < NE) atomicAdd(&deg[ei[e]], 1);
}

// --- device-wide exclusive scan of deg[] ---
__global__ __launch_bounds__(256) void scan1_kernel(const int* __restrict__ deg,
                                                    int* __restrict__ tmp,
                                                    int* __restrict__ bsum) {
    __shared__ int s[256];
    int i = blockIdx.x * 256 + threadIdx.x;
    int v = (i < NN) ? deg[i] : 0;
    s[threadIdx.x] = v;
    __syncthreads();
    for (int off = 1; off < 256; off <<= 1) {
        int t = (threadIdx.x >= off) ? s[threadIdx.x - off] : 0;
        __syncthreads();
        s[threadIdx.x] += t;
        __syncthreads();
    }
    if (i < NN) tmp[i] = s[threadIdx.x];
    if (threadIdx.x == 255) bsum[blockIdx.x] = s[255];
}

__global__ __launch_bounds__(512) void scan2_kernel(const int* __restrict__ bsum,
                                                    int* __restrict__ boff) {
    __shared__ int s[512];
    int t = threadIdx.x;
    int v = (t < NB) ? bsum[t] : 0;
    s[t] = v;
    __syncthreads();
    for (int off = 1; off < 512; off <<= 1) {
        int u = (t >= off) ? s[t - off] : 0;
        __syncthreads();
        s[t] += u;
        __syncthreads();
    }
    if (t < NB) boff[t] = s[t] - v;
}

__global__ __launch_bounds__(256) void scan3_kernel(const int* __restrict__ deg,
                                                    const int* __restrict__ tmp,
                                                    const int* __restrict__ boff,
                                                    int* __restrict__ row_ptr,
                                                    float* __restrict__ dinv) {
    int i = blockIdx.x * 256 + threadIdx.x;
    if (i >= NN) return;
    int d = deg[i];
    int start = tmp[i] - d + boff[blockIdx.x];
    row_ptr[i] = start;
    dinv[i] = (d > 0) ? rsqrtf((float)d) : 0.f;
    if (i == NN - 1) row_ptr[NN] = start + d;
}

__global__ __launch_bounds__(256) void fill_kernel(const int* __restrict__ ei,
                                                   const int* __restrict__ row_ptr,
                                                   int* __restrict__ cnt,
                                                   const float* __restrict__ dinv,
                                                   int2* __restrict__ csr) {
    int e = blockIdx.x * 256 + threadIdx.x;
    if (e >= NE) return;
    int r = ei[e];
    int c = ei[NE + e];
    int p = atomicAdd(&cnt[r], 1);
    csr[row_ptr[r] + p] = make_int2(c, (int)__float_as_uint(dinv[c]));
}

// Build WT[layer][cout][k] bf16, k = kb*64 + cin, from W[kb][cin][cout] f32.
__global__ __launch_bounds__(256) void wcat_kernel(const float* __restrict__ W1,
                                                   const float* __restrict__ W2,
                                                   const float* __restrict__ W3,
                                                   u16* __restrict__ WT) {
    int idx = blockIdx.x * 256 + threadIdx.x;  // 3 * 64 * 384
    if (idx >= 3 * 64 * 384) return;
    int l = idx / (64 * 384);
    int rem = idx - l * (64 * 384);
    int co = rem / 384;
    int kk = rem - co * 384;  // kb*64 + ci
    const float* W = (l == 0) ? W1 : ((l == 1) ? W2 : W3);
    WT[idx] = f2bf(W[kk * 64 + co]);
}

__global__ __launch_bounds__(256) void cvt_kernel(const float4* __restrict__ in,
                                                  ushort4* __restrict__ outb, int n4) {
    int i = blockIdx.x * 256 + threadIdx.x;
    if (i < n4) {
        float4 v = in[i];
        ushort4 u;
        u.x = f2bf(v.x); u.y = f2bf(v.y); u.z = f2bf(v.z); u.w = f2bf(v.w);
        outb[i] = u;
    }
}

// Lean propagate: t2 = P(t1) (FIRST) or 2*P(t1) - t0.  One wave = 4 nodes,
// lane = channel. Edge list pulled into lanes with one coalesced int2 load;
// readlane broadcasts make the t1 row-gathers independent (8 in flight).
template <bool FIRST>
__global__ __launch_bounds__(256, 8) void prop_kernel(
    const u16* __restrict__ t0, const u16* __restrict__ t1, u16* __restrict__ t2,
    const int2* __restrict__ csr, const int* __restrict__ row_ptr,
    const float* __restrict__ dinv) {
    int lane = threadIdx.x & 63;
    int wid = __builtin_amdgcn_readfirstlane((int)(threadIdx.x >> 6));
    int base = (blockIdx.x * 4 + wid) * 4;

    int sN[4], dN[4];
    int2 ce[4];
#pragma unroll
    for (int n = 0; n < 4; ++n) {
        int i = base + n;
        sN[n] = row_ptr[i];
        dN[n] = row_ptr[i + 1] - sN[n];
        ce[n] = make_int2(0, 0);
        if (dN[n] > 0) ce[n] = csr[sN[n] + min(lane, dN[n] - 1)];
    }

    float acc[4];
#pragma unroll
    for (int n = 0; n < 4; ++n) {
        acc[n] = 0.f;
        int d = dN[n];
        int r0 = min(d, 64);
#pragma unroll 8
        for (int k = 0; k < r0; ++k) {
            int col = __builtin_amdgcn_readlane(ce[n].x, k);
            float w = __uint_as_float((unsigned)__builtin_amdgcn_readlane(ce[n].y, k));
            acc[n] = fmaf(w, bf2f(t1[col * 64 + lane]), acc[n]);
        }
        for (int b = 64; b < d; b += 64) {  // Poisson(12): essentially never
            int rem = min(d - b, 64);
            int2 c2 = csr[sN[n] + b + min(lane, rem - 1)];
            for (int k = 0; k < rem; ++k) {
                int col = __builtin_amdgcn_readlane(c2.x, k);
                float w = __uint_as_float((unsigned)__builtin_amdgcn_readlane(c2.y, k));
                acc[n] = fmaf(w, bf2f(t1[col * 64 + lane]), acc[n]);
            }
        }
    }

#pragma unroll
    for (int n = 0; n < 4; ++n) {
        int i = base + n;
        float p = -dinv[i] * acc[n];
        float v = FIRST ? p : fmaf(2.f, p, -bf2f(t0[i * 64 + lane]));
        t2[i * 64 + lane] = f2bf(v);
    }
}

// MFMA GEMM: O[100000x64] = concat(T0..T5)[100000x384] @ Wcat[384x64] + bias.
// One wave = 16-node tile, all 64 couts: 4 n-tiles x 12 k-steps of
// mfma_f32_16x16x32_bf16. A-frag: row=lane&15, k=8*(lane>>4)+j (8 contiguous
// channels -> direct 16B global load). B from WT[cout][k] (contiguous k).
// C/D: col=lane&15, row=4*(lane>>4)+reg [verified m89 mapping].
// MODE 0: xout = bf16(relu(O));  MODE 1: fout = relu(O) + pos.
template <int MODE>
__global__ __launch_bounds__(256) void gemm_kernel(
    const u16* __restrict__ T0, const u16* __restrict__ T1, const u16* __restrict__ T2,
    const u16* __restrict__ T3, const u16* __restrict__ T4, const u16* __restrict__ T5,
    const u16* __restrict__ WT, const float* __restrict__ bias,
    u16* __restrict__ xout, float* __restrict__ fout, const float* __restrict__ pos) {
    int lane = threadIdx.x & 63;
    int wid = __builtin_amdgcn_readfirstlane((int)(threadIdx.x >> 6));
    int tile = blockIdx.x * 4 + wid;
    if (tile >= NTILE) return;
    int r = lane & 15;   // A-row within tile / D-col within n-tile
    int kg = lane >> 4;  // k-group
    int arow = tile * 16 + r;

    f32x4 acc[4];
#pragma unroll
    for (int t = 0; t < 4; ++t) {
        float b = bias[t * 16 + r];
        acc[t] = (f32x4){b, b, b, b};
    }

    const u16* Ts[6] = {T0, T1, T2, T3, T4, T5};
#pragma unroll
    for (int kb = 0; kb < 6; ++kb) {
        const u16* Tb = Ts[kb];
        short8 a0 = *(const short8*)(Tb + (size_t)arow * 64 + kg * 8);
        short8 a1 = *(const short8*)(Tb + (size_t)arow * 64 + 32 + kg * 8);
#pragma unroll
        for (int t = 0; t < 4; ++t) {
            const u16* wb = WT + (size_t)(t * 16 + r) * 384 + kb * 64 + kg * 8;
            short8 b0 = *(const short8*)(wb);
            short8 b1 = *(const short8*)(wb + 32);
            acc[t] = __builtin_amdgcn_mfma_f32_16x16x32_bf16(a0, b0, acc[t], 0, 0, 0);
            acc[t] = __builtin_amdgcn_mfma_f32_16x16x32_bf16(a1, b1, acc[t], 0, 0, 0);
        }
    }

#pragma unroll
    for (int t = 0; t < 4; ++t) {
#pragma unroll
        for (int rr = 0; rr < 4; ++rr) {
            int row = tile * 16 + kg * 4 + rr;
            int col = t * 16 + r;
            float v = acc[t][rr];
            if (MODE == 0) {
                xout[(size_t)row * 64 + col] = f2bf(fmaxf(v, 0.f));
            } else {
                fout[(size_t)row * 64 + col] = fmaxf(v, 0.f) + pos[(size_t)row * 64 + col];
            }
        }
    }
}

extern "C" void kernel_launch(void* const* d_in, const int* in_sizes, int n_in,
                              void* d_out, int out_size, void* d_ws, size_t ws_size,
                              hipStream_t stream) {
    const float* pos = (const float*)d_in[0];
    const int* ei = (const int*)d_in[1];
    const float* W1 = (const float*)d_in[2];
    const float* b1 = (const float*)d_in[3];
    const float* W2 = (const float*)d_in[4];
    const float* b2 = (const float*)d_in[5];
    const float* W3 = (const float*)d_in[6];
    const float* b3 = (const float*)d_in[7];
    float* out = (float*)d_out;

    char* ws = (char*)d_ws;
    size_t off = 0;
    auto alloc = [&](size_t bytes) {
        void* p = ws + off;
        off += (bytes + 1023) & ~(size_t)1023;
        return p;
    };
    int* deg = (int*)alloc(NN * 4);
    float* dinv = (float*)alloc(NN * 4);
    int* row_ptr = (int*)alloc((NN + 1) * 4);
    int* cnt = (int*)alloc(NN * 4);
    int* tmp = (int*)alloc(NN * 4);
    int* bsum = (int*)alloc(NB * 4);
    int* boff = (int*)alloc(NB * 4);
    int2* csr = (int2*)alloc((size_t)NE * 8);
    u16* WT = (u16*)alloc((size_t)3 * 64 * 384 * 2);
    u16* X = (u16*)alloc((size_t)NN * NC * 2);
    u16* T1 = (u16*)alloc((size_t)NN * NC * 2);
    u16* T2 = (u16*)alloc((size_t)NN * NC * 2);
    u16* T3 = (u16*)alloc((size_t)NN * NC * 2);
    u16* T4 = (u16*)alloc((size_t)NN * NC * 2);
    u16* T5 = (u16*)alloc((size_t)NN * NC * 2);

    hipMemsetAsync(deg, 0, NN * 4, stream);
    hipMemsetAsync(cnt, 0, NN * 4, stream);
    deg_kernel<<<(NE + 255) / 256, 256, 0, stream>>>(ei, deg);
    scan1_kernel<<<NB, 256, 0, stream>>>(deg, tmp, bsum);
    scan2_kernel<<<1, 512, 0, stream>>>(bsum, boff);
    scan3_kernel<<<NB, 256, 0, stream>>>(deg, tmp, boff, row_ptr, dinv);
    fill_kernel<<<(NE + 255) / 256, 256, 0, stream>>>(ei, row_ptr, cnt, dinv, csr);
    wcat_kernel<<<(3 * 64 * 384 + 255) / 256, 256, 0, stream>>>(W1, W2, W3, WT);

    const int G = NN / 16;               // 6250 blocks: 4 waves x 4 nodes
    const int G4 = (NN * NC / 4) / 256;  // 6250
    const int GG = (NTILE + 3) / 4;      // 1563 blocks: 4 wave-tiles each

    cvt_kernel<<<G4, 256, 0, stream>>>((const float4*)pos, (ushort4*)X, NN * NC / 4);

    // ---- layer 1 ----
    prop_kernel<true><<<G, 256, 0, stream>>>(X, X, T1, csr, row_ptr, dinv);
    prop_kernel<false><<<G, 256, 0, stream>>>(X, T1, T2, csr, row_ptr, dinv);
    prop_kernel<false><<<G, 256, 0, stream>>>(T1, T2, T3, csr, row_ptr, dinv);
    prop_kernel<false><<<G, 256, 0, stream>>>(T2, T3, T4, csr, row_ptr, dinv);
    prop_kernel<false><<<G, 256, 0, stream>>>(T3, T4, T5, csr, row_ptr, dinv);
    gemm_kernel<0><<<GG, 256, 0, stream>>>(X, T1, T2, T3, T4, T5, WT, b1, X, nullptr, nullptr);

    // ---- layer 2 ----
    prop_kernel<true><<<G, 256, 0, stream>>>(X, X, T1, csr, row_ptr, dinv);
    prop_kernel<false><<<G, 256, 0, stream>>>(X, T1, T2, csr, row_ptr, dinv);
    prop_kernel<false><<<G, 256, 0, stream>>>(T1, T2, T3, csr, row_ptr, dinv);
    prop_kernel<false><<<G, 256, 0, stream>>>(T2, T3, T4, csr, row_ptr, dinv);
    prop_kernel<false><<<G, 256, 0, stream>>>(T3, T4, T5, csr, row_ptr, dinv);
    gemm_kernel<0><<<GG, 256, 0, stream>>>(X, T1, T2, T3, T4, T5, WT + 24576, b2, X, nullptr, nullptr);

    // ---- layer 3 ----
    prop_kernel<true><<<G, 256, 0, stream>>>(X, X, T1, csr, row_ptr, dinv);
    prop_kernel<false><<<G, 256, 0, stream>>>(X, T1, T2, csr, row_ptr, dinv);
    prop_kernel<false><<<G, 256, 0, stream>>>(T1, T2, T3, csr, row_ptr, dinv);
    prop_kernel<false><<<G, 256, 0, stream>>>(T2, T3, T4, csr, row_ptr, dinv);
    prop_kernel<false><<<G, 256, 0, stream>>>(T3, T4, T5, csr, row_ptr, dinv);
    gemm_kernel<1><<<GG, 256, 0, stream>>>(X, T1, T2, T3, T4, T5, WT + 2 * 24576, b3, nullptr, out, pos);
}

// Round 10
// 894.547 us; speedup vs baseline: 3.2685x; 1.5496x over previous
//
#include <hip/hip_runtime.h>
#include <hip/hip_bf16.h>
#include <math.h>

#define NN 100000
#define NE 1200000
#define NC 64
#define NB 391     // ceil(NN/256)
#define NTILE 6250 // NN/16

typedef unsigned short u16;
typedef __attribute__((ext_vector_type(8))) short short8;
typedef __attribute__((ext_vector_type(4))) float f32x4;

__device__ __forceinline__ float bf2f(u16 u) {
    return __uint_as_float(((unsigned)u) << 16);
}
__device__ __forceinline__ u16 f2bf(float f) {
    __hip_bfloat16 h = __float2bfloat16(f);  // RTN
    return *reinterpret_cast<u16*>(&h);
}

__global__ __launch_bounds__(256) void deg_kernel(const int* __restrict__ ei, int* __restrict__ deg) {
    int e = blockIdx.x * 256 + threadIdx.x;
    if (e < NE) atomicAdd(&deg[ei[e]], 1);
}

// --- device-wide exclusive scan of deg[] ---
__global__ __launch_bounds__(256) void scan1_kernel(const int* __restrict__ deg,
                                                    int* __restrict__ tmp,
                                                    int* __restrict__ bsum) {
    __shared__ int s[256];
    int i = blockIdx.x * 256 + threadIdx.x;
    int v = (i < NN) ? deg[i] : 0;
    s[threadIdx.x] = v;
    __syncthreads();
    for (int off = 1; off < 256; off <<= 1) {
        int t = (threadIdx.x >= off) ? s[threadIdx.x - off] : 0;
        __syncthreads();
        s[threadIdx.x] += t;
        __syncthreads();
    }
    if (i < NN) tmp[i] = s[threadIdx.x];
    if (threadIdx.x == 255) bsum[blockIdx.x] = s[255];
}

__global__ __launch_bounds__(512) void scan2_kernel(const int* __restrict__ bsum,
                                                    int* __restrict__ boff) {
    __shared__ int s[512];
    int t = threadIdx.x;
    int v = (t < NB) ? bsum[t] : 0;
    s[t] = v;
    __syncthreads();
    for (int off = 1; off < 512; off <<= 1) {
        int u = (t >= off) ? s[t - off] : 0;
        __syncthreads();
        s[t] += u;
        __syncthreads();
    }
    if (t < NB) boff[t] = s[t] - v;
}

__global__ __launch_bounds__(256) void scan3_kernel(const int* __restrict__ deg,
                                                    const int* __restrict__ tmp,
                                                    const int* __restrict__ boff,
                                                    int* __restrict__ row_ptr,
                                                    float* __restrict__ dinv) {
    int i = blockIdx.x * 256 + threadIdx.x;
    if (i >= NN) return;
    int d = deg[i];
    int start = tmp[i] - d + boff[blockIdx.x];
    row_ptr[i] = start;
    dinv[i] = (d > 0) ? rsqrtf((float)d) : 0.f;
    if (i == NN - 1) row_ptr[NN] = start + d;
}

__global__ __launch_bounds__(256) void fill_kernel(const int* __restrict__ ei,
                                                   const int* __restrict__ row_ptr,
                                                   int* __restrict__ cnt,
                                                   const float* __restrict__ dinv,
                                                   int2* __restrict__ csr) {
    int e = blockIdx.x * 256 + threadIdx.x;
    if (e >= NE) return;
    int r = ei[e];
    int c = ei[NE + e];
    int p = atomicAdd(&cnt[r], 1);
    csr[row_ptr[r] + p] = make_int2(c, (int)__float_as_uint(dinv[c]));
}

// Build WT[layer][cout][k] bf16, k = kb*64 + cin, from W[kb][cin][cout] f32.
__global__ __launch_bounds__(256) void wcat_kernel(const float* __restrict__ W1,
                                                   const float* __restrict__ W2,
                                                   const float* __restrict__ W3,
                                                   u16* __restrict__ WT) {
    int idx = blockIdx.x * 256 + threadIdx.x;  // 3 * 64 * 384
    if (idx >= 3 * 64 * 384) return;
    int l = idx / (64 * 384);
    int rem = idx - l * (64 * 384);
    int co = rem / 384;
    int kk = rem - co * 384;  // kb*64 + ci
    const float* W = (l == 0) ? W1 : ((l == 1) ? W2 : W3);
    WT[idx] = f2bf(W[kk * 64 + co]);
}

__global__ __launch_bounds__(256) void cvt_kernel(const float4* __restrict__ in,
                                                  ushort4* __restrict__ outb, int n4) {
    int i = blockIdx.x * 256 + threadIdx.x;
    if (i < n4) {
        float4 v = in[i];
        ushort4 u;
        u.x = f2bf(v.x); u.y = f2bf(v.y); u.z = f2bf(v.z); u.w = f2bf(v.w);
        outb[i] = u;
    }
}

// Lean propagate: t2 = P(t1) (FIRST) or 2*P(t1) - t0.  One wave = 4 nodes,
// lane = channel. The 4 nodes' edge loops are INTERLEAVED on a wave-uniform
// bound kmax: each k-iteration issues 4 independent gathers (one per acc
// chain), predicated by w=(k<dN)?w:0 with the edge register pre-clamped to
// a valid duplicate address. Unroll-4 over k -> ~16 loads in flight.
template <bool FIRST>
__global__ __launch_bounds__(256, 6) void prop_kernel(
    const u16* __restrict__ t0, const u16* __restrict__ t1, u16* __restrict__ t2,
    const int2* __restrict__ csr, const int* __restrict__ row_ptr,
    const float* __restrict__ dinv) {
    int lane = threadIdx.x & 63;
    int wid = __builtin_amdgcn_readfirstlane((int)(threadIdx.x >> 6));
    int base = (blockIdx.x * 4 + wid) * 4;

    int sN[4], dN[4];
    int2 ce[4];
#pragma unroll
    for (int n = 0; n < 4; ++n) {
        int i = base + n;
        sN[n] = row_ptr[i];
        dN[n] = row_ptr[i + 1] - sN[n];
        ce[n] = make_int2(0, 0);
        if (dN[n] > 0) ce[n] = csr[sN[n] + min(lane, dN[n] - 1)];
    }

    // hoisted independent loads (overlap with the gather loop)
    float dv[4], x0[4];
#pragma unroll
    for (int n = 0; n < 4; ++n) {
        dv[n] = dinv[base + n];
        x0[n] = 0.f;
        if (!FIRST) x0[n] = bf2f(t0[(size_t)(base + n) * 64 + lane]);
    }

    int kmax = max(max(min(dN[0], 64), min(dN[1], 64)),
                   max(min(dN[2], 64), min(dN[3], 64)));  // wave-uniform

    float acc[4] = {0.f, 0.f, 0.f, 0.f};
#pragma unroll 4
    for (int k = 0; k < kmax; ++k) {
#pragma unroll
        for (int n = 0; n < 4; ++n) {
            int col = __builtin_amdgcn_readlane(ce[n].x, k);
            float w = __uint_as_float((unsigned)__builtin_amdgcn_readlane(ce[n].y, k));
            w = (k < dN[n]) ? w : 0.f;
            acc[n] = fmaf(w, bf2f(t1[(size_t)col * 64 + lane]), acc[n]);
        }
    }

    // rare tail: degree > 64 (Poisson(12) -> essentially never)
#pragma unroll
    for (int n = 0; n < 4; ++n) {
        for (int b = 64; b < dN[n]; b += 64) {
            int rem = min(dN[n] - b, 64);
            int2 c2 = csr[sN[n] + b + min(lane, rem - 1)];
            for (int k = 0; k < rem; ++k) {
                int col = __builtin_amdgcn_readlane(c2.x, k);
                float w = __uint_as_float((unsigned)__builtin_amdgcn_readlane(c2.y, k));
                acc[n] = fmaf(w, bf2f(t1[(size_t)col * 64 + lane]), acc[n]);
            }
        }
    }

#pragma unroll
    for (int n = 0; n < 4; ++n) {
        float p = -dv[n] * acc[n];
        float v = FIRST ? p : fmaf(2.f, p, -x0[n]);
        t2[(size_t)(base + n) * 64 + lane] = f2bf(v);
    }
}

// MFMA GEMM: O[100000x64] = concat(T0..T5)[100000x384] @ Wcat[384x64] + bias.
// One wave = 16-node tile, all 64 couts: 4 n-tiles x 12 k-steps of
// mfma_f32_16x16x32_bf16. A-frag: row=lane&15, k=8*(lane>>4)+j (8 contiguous
// channels -> direct 16B global load). B from WT[cout][k] (contiguous k).
// C/D: col=lane&15, row=4*(lane>>4)+reg [verified m89 mapping].
// MODE 0: xout = bf16(relu(O));  MODE 1: fout = relu(O) + pos.
template <int MODE>
__global__ __launch_bounds__(256) void gemm_kernel(
    const u16* __restrict__ T0, const u16* __restrict__ T1, const u16* __restrict__ T2,
    const u16* __restrict__ T3, const u16* __restrict__ T4, const u16* __restrict__ T5,
    const u16* __restrict__ WT, const float* __restrict__ bias,
    u16* __restrict__ xout, float* __restrict__ fout, const float* __restrict__ pos) {
    int lane = threadIdx.x & 63;
    int wid = __builtin_amdgcn_readfirstlane((int)(threadIdx.x >> 6));
    int tile = blockIdx.x * 4 + wid;
    if (tile >= NTILE) return;
    int r = lane & 15;   // A-row within tile / D-col within n-tile
    int kg = lane >> 4;  // k-group
    int arow = tile * 16 + r;

    f32x4 acc[4];
#pragma unroll
    for (int t = 0; t < 4; ++t) {
        float b = bias[t * 16 + r];
        acc[t] = (f32x4){b, b, b, b};
    }

    const u16* Ts[6] = {T0, T1, T2, T3, T4, T5};
#pragma unroll
    for (int kb = 0; kb < 6; ++kb) {
        const u16* Tb = Ts[kb];
        short8 a0 = *(const short8*)(Tb + (size_t)arow * 64 + kg * 8);
        short8 a1 = *(const short8*)(Tb + (size_t)arow * 64 + 32 + kg * 8);
#pragma unroll
        for (int t = 0; t < 4; ++t) {
            const u16* wb = WT + (size_t)(t * 16 + r) * 384 + kb * 64 + kg * 8;
            short8 b0 = *(const short8*)(wb);
            short8 b1 = *(const short8*)(wb + 32);
            acc[t] = __builtin_amdgcn_mfma_f32_16x16x32_bf16(a0, b0, acc[t], 0, 0, 0);
            acc[t] = __builtin_amdgcn_mfma_f32_16x16x32_bf16(a1, b1, acc[t], 0, 0, 0);
        }
    }

#pragma unroll
    for (int t = 0; t < 4; ++t) {
#pragma unroll
        for (int rr = 0; rr < 4; ++rr) {
            int row = tile * 16 + kg * 4 + rr;
            int col = t * 16 + r;
            float v = acc[t][rr];
            if (MODE == 0) {
                xout[(size_t)row * 64 + col] = f2bf(fmaxf(v, 0.f));
            } else {
                fout[(size_t)row * 64 + col] = fmaxf(v, 0.f) + pos[(size_t)row * 64 + col];
            }
        }
    }
}

extern "C" void kernel_launch(void* const* d_in, const int* in_sizes, int n_in,
                              void* d_out, int out_size, void* d_ws, size_t ws_size,
                              hipStream_t stream) {
    const float* pos = (const float*)d_in[0];
    const int* ei = (const int*)d_in[1];
    const float* W1 = (const float*)d_in[2];
    const float* b1 = (const float*)d_in[3];
    const float* W2 = (const float*)d_in[4];
    const float* b2 = (const float*)d_in[5];
    const float* W3 = (const float*)d_in[6];
    const float* b3 = (const float*)d_in[7];
    float* out = (float*)d_out;

    char* ws = (char*)d_ws;
    size_t off = 0;
    auto alloc = [&](size_t bytes) {
        void* p = ws + off;
        off += (bytes + 1023) & ~(size_t)1023;
        return p;
    };
    int* deg = (int*)alloc(NN * 4);
    float* dinv = (float*)alloc(NN * 4);
    int* row_ptr = (int*)alloc((NN + 1) * 4);
    int* cnt = (int*)alloc(NN * 4);
    int* tmp = (int*)alloc(NN * 4);
    int* bsum = (int*)alloc(NB * 4);
    int* boff = (int*)alloc(NB * 4);
    int2* csr = (int2*)alloc((size_t)NE * 8);
    u16* WT = (u16*)alloc((size_t)3 * 64 * 384 * 2);
    u16* X = (u16*)alloc((size_t)NN * NC * 2);
    u16* T1 = (u16*)alloc((size_t)NN * NC * 2);
    u16* T2 = (u16*)alloc((size_t)NN * NC * 2);
    u16* T3 = (u16*)alloc((size_t)NN * NC * 2);
    u16* T4 = (u16*)alloc((size_t)NN * NC * 2);
    u16* T5 = (u16*)alloc((size_t)NN * NC * 2);

    hipMemsetAsync(deg, 0, NN * 4, stream);
    hipMemsetAsync(cnt, 0, NN * 4, stream);
    deg_kernel<<<(NE + 255) / 256, 256, 0, stream>>>(ei, deg);
    scan1_kernel<<<NB, 256, 0, stream>>>(deg, tmp, bsum);
    scan2_kernel<<<1, 512, 0, stream>>>(bsum, boff);
    scan3_kernel<<<NB, 256, 0, stream>>>(deg, tmp, boff, row_ptr, dinv);
    fill_kernel<<<(NE + 255) / 256, 256, 0, stream>>>(ei, row_ptr, cnt, dinv, csr);
    wcat_kernel<<<(3 * 64 * 384 + 255) / 256, 256, 0, stream>>>(W1, W2, W3, WT);

    const int G = NN / 16;               // 6250 blocks: 4 waves x 4 nodes
    const int G4 = (NN * NC / 4) / 256;  // 6250
    const int GG = (NTILE + 3) / 4;      // 1563 blocks: 4 wave-tiles each

    cvt_kernel<<<G4, 256, 0, stream>>>((const float4*)pos, (ushort4*)X, NN * NC / 4);

    // ---- layer 1 ----
    prop_kernel<true><<<G, 256, 0, stream>>>(X, X, T1, csr, row_ptr, dinv);
    prop_kernel<false><<<G, 256, 0, stream>>>(X, T1, T2, csr, row_ptr, dinv);
    prop_kernel<false><<<G, 256, 0, stream>>>(T1, T2, T3, csr, row_ptr, dinv);
    prop_kernel<false><<<G, 256, 0, stream>>>(T2, T3, T4, csr, row_ptr, dinv);
    prop_kernel<false><<<G, 256, 0, stream>>>(T3, T4, T5, csr, row_ptr, dinv);
    gemm_kernel<0><<<GG, 256, 0, stream>>>(X, T1, T2, T3, T4, T5, WT, b1, X, nullptr, nullptr);

    // ---- layer 2 ----
    prop_kernel<true><<<G, 256, 0, stream>>>(X, X, T1, csr, row_ptr, dinv);
    prop_kernel<false><<<G, 256, 0, stream>>>(X, T1, T2, csr, row_ptr, dinv);
    prop_kernel<false><<<G, 256, 0, stream>>>(T1, T2, T3, csr, row_ptr, dinv);
    prop_kernel<false><<<G, 256, 0, stream>>>(T2, T3, T4, csr, row_ptr, dinv);
    prop_kernel<false><<<G, 256, 0, stream>>>(T3, T4, T5, csr, row_ptr, dinv);
    gemm_kernel<0><<<GG, 256, 0, stream>>>(X, T1, T2, T3, T4, T5, WT + 24576, b2, X, nullptr, nullptr);

    // ---- layer 3 ----
    prop_kernel<true><<<G, 256, 0, stream>>>(X, X, T1, csr, row_ptr, dinv);
    prop_kernel<false><<<G, 256, 0, stream>>>(X, T1, T2, csr, row_ptr, dinv);
    prop_kernel<false><<<G, 256, 0, stream>>>(T1, T2, T3, csr, row_ptr, dinv);
    prop_kernel<false><<<G, 256, 0, stream>>>(T2, T3, T4, csr, row_ptr, dinv);
    prop_kernel<false><<<G, 256, 0, stream>>>(T3, T4, T5, csr, row_ptr, dinv);
    gemm_kernel<1><<<GG, 256, 0, stream>>>(X, T1, T2, T3, T4, T5, WT + 2 * 24576, b3, nullptr, out, pos);
}

// Round 11
// 892.710 us; speedup vs baseline: 3.2752x; 1.0021x over previous
//
#include <hip/hip_runtime.h>
#include <hip/hip_bf16.h>
#include <math.h>

#define NN 100000
#define NE 1200000
#define NC 64
#define NB 391     // ceil(NN/256)
#define NTILE 6250 // NN/16

typedef unsigned short u16;
typedef __attribute__((ext_vector_type(8))) short short8;
typedef __attribute__((ext_vector_type(4))) float f32x4;

__device__ __forceinline__ float bf2f(u16 u) {
    return __uint_as_float(((unsigned)u) << 16);
}
__device__ __forceinline__ u16 f2bf(float f) {
    __hip_bfloat16 h = __float2bfloat16(f);  // RTN
    return *reinterpret_cast<u16*>(&h);
}

// deg pass also records each edge's arrival slot -> fill needs no atomics.
__global__ __launch_bounds__(256) void deg_kernel(const int* __restrict__ ei,
                                                  int* __restrict__ deg,
                                                  int* __restrict__ ppos) {
    int e = blockIdx.x * 256 + threadIdx.x;
    if (e < NE) ppos[e] = atomicAdd(&deg[ei[e]], 1);
}

// --- device-wide exclusive scan of deg[] ---
__global__ __launch_bounds__(256) void scan1_kernel(const int* __restrict__ deg,
                                                    int* __restrict__ tmp,
                                                    int* __restrict__ bsum) {
    __shared__ int s[256];
    int i = blockIdx.x * 256 + threadIdx.x;
    int v = (i < NN) ? deg[i] : 0;
    s[threadIdx.x] = v;
    __syncthreads();
    for (int off = 1; off < 256; off <<= 1) {
        int t = (threadIdx.x >= off) ? s[threadIdx.x - off] : 0;
        __syncthreads();
        s[threadIdx.x] += t;
        __syncthreads();
    }
    if (i < NN) tmp[i] = s[threadIdx.x];
    if (threadIdx.x == 255) bsum[blockIdx.x] = s[255];
}

__global__ __launch_bounds__(512) void scan2_kernel(const int* __restrict__ bsum,
                                                    int* __restrict__ boff) {
    __shared__ int s[512];
    int t = threadIdx.x;
    int v = (t < NB) ? bsum[t] : 0;
    s[t] = v;
    __syncthreads();
    for (int off = 1; off < 512; off <<= 1) {
        int u = (t >= off) ? s[t - off] : 0;
        __syncthreads();
        s[t] += u;
        __syncthreads();
    }
    if (t < NB) boff[t] = s[t] - v;
}

__global__ __launch_bounds__(256) void scan3_kernel(const int* __restrict__ deg,
                                                    const int* __restrict__ tmp,
                                                    const int* __restrict__ boff,
                                                    int* __restrict__ row_ptr,
                                                    float* __restrict__ dinv) {
    int i = blockIdx.x * 256 + threadIdx.x;
    if (i >= NN) return;
    int d = deg[i];
    int start = tmp[i] - d + boff[blockIdx.x];
    row_ptr[i] = start;
    dinv[i] = (d > 0) ? rsqrtf((float)d) : 0.f;
    if (i == NN - 1) row_ptr[NN] = start + d;
}

__global__ __launch_bounds__(256) void fill_kernel(const int* __restrict__ ei,
                                                   const int* __restrict__ row_ptr,
                                                   const int* __restrict__ ppos,
                                                   const float* __restrict__ dinv,
                                                   int2* __restrict__ csr) {
    int e = blockIdx.x * 256 + threadIdx.x;
    if (e >= NE) return;
    int r = ei[e];
    int c = ei[NE + e];
    csr[row_ptr[r] + ppos[e]] = make_int2(c, (int)__float_as_uint(dinv[c]));
}

// Build WT[layer][cout][k] bf16, k = kb*64 + cin, from W[kb][cin][cout] f32.
__global__ __launch_bounds__(256) void wcat_kernel(const float* __restrict__ W1,
                                                   const float* __restrict__ W2,
                                                   const float* __restrict__ W3,
                                                   u16* __restrict__ WT) {
    int idx = blockIdx.x * 256 + threadIdx.x;  // 3 * 64 * 384
    if (idx >= 3 * 64 * 384) return;
    int l = idx / (64 * 384);
    int rem = idx - l * (64 * 384);
    int co = rem / 384;
    int kk = rem - co * 384;  // kb*64 + ci
    const float* W = (l == 0) ? W1 : ((l == 1) ? W2 : W3);
    WT[idx] = f2bf(W[kk * 64 + co]);
}

__global__ __launch_bounds__(256) void cvt_kernel(const float4* __restrict__ in,
                                                  ushort4* __restrict__ outb, int n4) {
    int i = blockIdx.x * 256 + threadIdx.x;
    if (i < n4) {
        float4 v = in[i];
        ushort4 u;
        u.x = f2bf(v.x); u.y = f2bf(v.y); u.z = f2bf(v.z); u.w = f2bf(v.w);
        outb[i] = u;
    }
}

// Lean propagate: t2 = P(t1) (FIRST) or 2*P(t1) - t0.  One wave = 4 nodes.
// PAIRED-EDGE gather: lanes 0-31 process even edges, lanes 32-63 odd edges;
// each lane loads 4B = 2 bf16 channels, so ONE load instruction fetches two
// t1 rows. Unroll-4 x 4 nodes -> 16 load instrs = 32 rows in flight.
// Epilogue: cross-half __shfl_xor(32) reduce, half-0 lanes store packed u32.
template <bool FIRST>
__global__ __launch_bounds__(256, 6) void prop_kernel(
    const u16* __restrict__ t0, const u16* __restrict__ t1, u16* __restrict__ t2,
    const int2* __restrict__ csr, const int* __restrict__ row_ptr,
    const float* __restrict__ dinv) {
    int lane = threadIdx.x & 63;
    int wid = __builtin_amdgcn_readfirstlane((int)(threadIdx.x >> 6));
    int base = (blockIdx.x * 4 + wid) * 4;
    int half = lane >> 5;  // 0: even edge of pair, 1: odd
    int ch2 = lane & 31;   // channel pair: channels 2*ch2, 2*ch2+1

    int sN[4], dN[4];
    int2 ce[4];
#pragma unroll
    for (int n = 0; n < 4; ++n) {
        int i = base + n;
        sN[n] = row_ptr[i];
        dN[n] = row_ptr[i + 1] - sN[n];
        ce[n] = make_int2(0, 0);
        if (dN[n] > 0) ce[n] = csr[sN[n] + min(lane, dN[n] - 1)];
    }

    float dv[4];
    unsigned x0u[4];
#pragma unroll
    for (int n = 0; n < 4; ++n) {
        dv[n] = dinv[base + n];
        x0u[n] = 0u;
        if (!FIRST) x0u[n] = *(const unsigned*)(t0 + (size_t)(base + n) * 64 + ch2 * 2);
    }

    int kmax = max(max(min(dN[0], 64), min(dN[1], 64)),
                   max(min(dN[2], 64), min(dN[3], 64)));  // wave-uniform

    float acc0[4] = {0.f, 0.f, 0.f, 0.f};
    float acc1[4] = {0.f, 0.f, 0.f, 0.f};
#pragma unroll 4
    for (int k = 0; k < kmax; k += 2) {  // k even, k+1 <= 63
#pragma unroll
        for (int n = 0; n < 4; ++n) {
            int colA = __builtin_amdgcn_readlane(ce[n].x, k);
            int colB = __builtin_amdgcn_readlane(ce[n].x, k + 1);
            float wA = __uint_as_float((unsigned)__builtin_amdgcn_readlane(ce[n].y, k));
            float wB = __uint_as_float((unsigned)__builtin_amdgcn_readlane(ce[n].y, k + 1));
            int col = half ? colB : colA;
            float w = half ? wB : wA;
            w = ((k + half) < dN[n]) ? w : 0.f;
            unsigned v = *(const unsigned*)(t1 + (size_t)col * 64 + ch2 * 2);
            acc0[n] = fmaf(w, __uint_as_float(v << 16), acc0[n]);
            acc1[n] = fmaf(w, __uint_as_float(v & 0xffff0000u), acc1[n]);
        }
    }

    // rare tail: degree > 64 (Poisson(12) -> essentially never)
#pragma unroll
    for (int n = 0; n < 4; ++n) {
        for (int b = 64; b < dN[n]; b += 64) {
            int rem = min(dN[n] - b, 64);
            int2 c2 = csr[sN[n] + b + min(lane, rem - 1)];
            for (int k = 0; k < rem; k += 2) {
                int colA = __builtin_amdgcn_readlane(c2.x, k);
                int colB = __builtin_amdgcn_readlane(c2.x, min(k + 1, 63));
                float wA = __uint_as_float((unsigned)__builtin_amdgcn_readlane(c2.y, k));
                float wB = __uint_as_float((unsigned)__builtin_amdgcn_readlane(c2.y, min(k + 1, 63)));
                int col = half ? colB : colA;
                float w = half ? wB : wA;
                w = ((k + half) < rem) ? w : 0.f;
                unsigned v = *(const unsigned*)(t1 + (size_t)col * 64 + ch2 * 2);
                acc0[n] = fmaf(w, __uint_as_float(v << 16), acc0[n]);
                acc1[n] = fmaf(w, __uint_as_float(v & 0xffff0000u), acc1[n]);
            }
        }
    }

#pragma unroll
    for (int n = 0; n < 4; ++n) {
        float s0 = acc0[n] + __shfl_xor(acc0[n], 32);
        float s1 = acc1[n] + __shfl_xor(acc1[n], 32);
        float p0 = -dv[n] * s0;
        float p1 = -dv[n] * s1;
        float v0, v1;
        if (FIRST) {
            v0 = p0; v1 = p1;
        } else {
            v0 = fmaf(2.f, p0, -__uint_as_float(x0u[n] << 16));
            v1 = fmaf(2.f, p1, -__uint_as_float(x0u[n] & 0xffff0000u));
        }
        if (half == 0) {
            unsigned o = (unsigned)f2bf(v0) | ((unsigned)f2bf(v1) << 16);
            *(unsigned*)(t2 + (size_t)(base + n) * 64 + ch2 * 2) = o;
        }
    }
}

// MFMA GEMM: O[100000x64] = concat(T0..T5)[100000x384] @ Wcat[384x64] + bias.
// One wave = 16-node tile, all 64 couts: 4 n-tiles x 12 k-steps of
// mfma_f32_16x16x32_bf16. A-frag: row=lane&15, k=8*(lane>>4)+j (8 contiguous
// channels -> direct 16B global load). B from WT[cout][k] (contiguous k).
// C/D: col=lane&15, row=4*(lane>>4)+reg [verified m89 mapping].
// MODE 0: xout = bf16(relu(O));  MODE 1: fout = relu(O) + pos.
template <int MODE>
__global__ __launch_bounds__(256) void gemm_kernel(
    const u16* __restrict__ T0, const u16* __restrict__ T1, const u16* __restrict__ T2,
    const u16* __restrict__ T3, const u16* __restrict__ T4, const u16* __restrict__ T5,
    const u16* __restrict__ WT, const float* __restrict__ bias,
    u16* __restrict__ xout, float* __restrict__ fout, const float* __restrict__ pos) {
    int lane = threadIdx.x & 63;
    int wid = __builtin_amdgcn_readfirstlane((int)(threadIdx.x >> 6));
    int tile = blockIdx.x * 4 + wid;
    if (tile >= NTILE) return;
    int r = lane & 15;   // A-row within tile / D-col within n-tile
    int kg = lane >> 4;  // k-group
    int arow = tile * 16 + r;

    f32x4 acc[4];
#pragma unroll
    for (int t = 0; t < 4; ++t) {
        float b = bias[t * 16 + r];
        acc[t] = (f32x4){b, b, b, b};
    }

    const u16* Ts[6] = {T0, T1, T2, T3, T4, T5};
#pragma unroll
    for (int kb = 0; kb < 6; ++kb) {
        const u16* Tb = Ts[kb];
        short8 a0 = *(const short8*)(Tb + (size_t)arow * 64 + kg * 8);
        short8 a1 = *(const short8*)(Tb + (size_t)arow * 64 + 32 + kg * 8);
#pragma unroll
        for (int t = 0; t < 4; ++t) {
            const u16* wb = WT + (size_t)(t * 16 + r) * 384 + kb * 64 + kg * 8;
            short8 b0 = *(const short8*)(wb);
            short8 b1 = *(const short8*)(wb + 32);
            acc[t] = __builtin_amdgcn_mfma_f32_16x16x32_bf16(a0, b0, acc[t], 0, 0, 0);
            acc[t] = __builtin_amdgcn_mfma_f32_16x16x32_bf16(a1, b1, acc[t], 0, 0, 0);
        }
    }

#pragma unroll
    for (int t = 0; t < 4; ++t) {
#pragma unroll
        for (int rr = 0; rr < 4; ++rr) {
            int row = tile * 16 + kg * 4 + rr;
            int col = t * 16 + r;
            float v = acc[t][rr];
            if (MODE == 0) {
                xout[(size_t)row * 64 + col] = f2bf(fmaxf(v, 0.f));
            } else {
                fout[(size_t)row * 64 + col] = fmaxf(v, 0.f) + pos[(size_t)row * 64 + col];
            }
        }
    }
}

extern "C" void kernel_launch(void* const* d_in, const int* in_sizes, int n_in,
                              void* d_out, int out_size, void* d_ws, size_t ws_size,
                              hipStream_t stream) {
    const float* pos = (const float*)d_in[0];
    const int* ei = (const int*)d_in[1];
    const float* W1 = (const float*)d_in[2];
    const float* b1 = (const float*)d_in[3];
    const float* W2 = (const float*)d_in[4];
    const float* b2 = (const float*)d_in[5];
    const float* W3 = (const float*)d_in[6];
    const float* b3 = (const float*)d_in[7];
    float* out = (float*)d_out;

    char* ws = (char*)d_ws;
    size_t off = 0;
    auto alloc = [&](size_t bytes) {
        void* p = ws + off;
        off += (bytes + 1023) & ~(size_t)1023;
        return p;
    };
    int* deg = (int*)alloc(NN * 4);
    float* dinv = (float*)alloc(NN * 4);
    int* row_ptr = (int*)alloc((NN + 1) * 4);
    int* tmp = (int*)alloc(NN * 4);
    int* bsum = (int*)alloc(NB * 4);
    int* boff = (int*)alloc(NB * 4);
    int* ppos = (int*)alloc((size_t)NE * 4);
    int2* csr = (int2*)alloc((size_t)NE * 8);
    u16* WT = (u16*)alloc((size_t)3 * 64 * 384 * 2);
    u16* X = (u16*)alloc((size_t)NN * NC * 2);
    u16* T1 = (u16*)alloc((size_t)NN * NC * 2);
    u16* T2 = (u16*)alloc((size_t)NN * NC * 2);
    u16* T3 = (u16*)alloc((size_t)NN * NC * 2);
    u16* T4 = (u16*)alloc((size_t)NN * NC * 2);
    u16* T5 = (u16*)alloc((size_t)NN * NC * 2);

    hipMemsetAsync(deg, 0, NN * 4, stream);
    deg_kernel<<<(NE + 255) / 256, 256, 0, stream>>>(ei, deg, ppos);
    scan1_kernel<<<NB, 256, 0, stream>>>(deg, tmp, bsum);
    scan2_kernel<<<1, 512, 0, stream>>>(bsum, boff);
    scan3_kernel<<<NB, 256, 0, stream>>>(deg, tmp, boff, row_ptr, dinv);
    fill_kernel<<<(NE + 255) / 256, 256, 0, stream>>>(ei, row_ptr, ppos, dinv, csr);
    wcat_kernel<<<(3 * 64 * 384 + 255) / 256, 256, 0, stream>>>(W1, W2, W3, WT);

    const int G = NN / 16;               // 6250 blocks: 4 waves x 4 nodes
    const int G4 = (NN * NC / 4) / 256;  // 6250
    const int GG = (NTILE + 3) / 4;      // 1563 blocks: 4 wave-tiles each

    cvt_kernel<<<G4, 256, 0, stream>>>((const float4*)pos, (ushort4*)X, NN * NC / 4);

    // ---- layer 1 ----
    prop_kernel<true><<<G, 256, 0, stream>>>(X, X, T1, csr, row_ptr, dinv);
    prop_kernel<false><<<G, 256, 0, stream>>>(X, T1, T2, csr, row_ptr, dinv);
    prop_kernel<false><<<G, 256, 0, stream>>>(T1, T2, T3, csr, row_ptr, dinv);
    prop_kernel<false><<<G, 256, 0, stream>>>(T2, T3, T4, csr, row_ptr, dinv);
    prop_kernel<false><<<G, 256, 0, stream>>>(T3, T4, T5, csr, row_ptr, dinv);
    gemm_kernel<0><<<GG, 256, 0, stream>>>(X, T1, T2, T3, T4, T5, WT, b1, X, nullptr, nullptr);

    // ---- layer 2 ----
    prop_kernel<true><<<G, 256, 0, stream>>>(X, X, T1, csr, row_ptr, dinv);
    prop_kernel<false><<<G, 256, 0, stream>>>(X, T1, T2, csr, row_ptr, dinv);
    prop_kernel<false><<<G, 256, 0, stream>>>(T1, T2, T3, csr, row_ptr, dinv);
    prop_kernel<false><<<G, 256, 0, stream>>>(T2, T3, T4, csr, row_ptr, dinv);
    prop_kernel<false><<<G, 256, 0, stream>>>(T3, T4, T5, csr, row_ptr, dinv);
    gemm_kernel<0><<<GG, 256, 0, stream>>>(X, T1, T2, T3, T4, T5, WT + 24576, b2, X, nullptr, nullptr);

    // ---- layer 3 ----
    prop_kernel<true><<<G, 256, 0, stream>>>(X, X, T1, csr, row_ptr, dinv);
    prop_kernel<false><<<G, 256, 0, stream>>>(X, T1, T2, csr, row_ptr, dinv);
    prop_kernel<false><<<G, 256, 0, stream>>>(T1, T2, T3, csr, row_ptr, dinv);
    prop_kernel<false><<<G, 256, 0, stream>>>(T2, T3, T4, csr, row_ptr, dinv);
    prop_kernel<false><<<G, 256, 0, stream>>>(T3, T4, T5, csr, row_ptr, dinv);
    gemm_kernel<1><<<GG, 256, 0, stream>>>(X, T1, T2, T3, T4, T5, WT + 2 * 24576, b3, nullptr, out, pos);
}

// Round 15
// 848.968 us; speedup vs baseline: 3.4440x; 1.0515x over previous
//
#include <hip/hip_runtime.h>
#include <hip/hip_bf16.h>
#include <math.h>

#define NN 100000
#define NE 1200000
#define NC 64
#define NB 391     // ceil(NN/256)
#define NTILE 6250 // NN/16
#define NT2 3125   // NN/32 supertiles
#define WSTRIDE 392  // padded LDS row stride (u16) for WT; 784B, 16B-aligned

typedef unsigned short u16;
typedef unsigned int u32;
typedef __attribute__((ext_vector_type(8))) short short8;
typedef __attribute__((ext_vector_type(4))) float f32x4;

__device__ __forceinline__ float bflo(u32 u) { return __uint_as_float(u << 16); }
__device__ __forceinline__ float bfhi(u32 u) { return __uint_as_float(u & 0xffff0000u); }
__device__ __forceinline__ u16 f2bf(float f) {
    __hip_bfloat16 h = __float2bfloat16(f);  // RTN
    return *reinterpret_cast<u16*>(&h);
}

// deg pass also records each edge's arrival slot -> fill needs no atomics.
__global__ __launch_bounds__(256) void deg_kernel(const int* __restrict__ ei,
                                                  int* __restrict__ deg,
                                                  int* __restrict__ ppos) {
    int e = blockIdx.x * 256 + threadIdx.x;
    if (e < NE) ppos[e] = atomicAdd(&deg[ei[e]], 1);
}

// --- device-wide exclusive scan of deg[] ---
__global__ __launch_bounds__(256) void scan1_kernel(const int* __restrict__ deg,
                                                    int* __restrict__ tmp,
                                                    int* __restrict__ bsum) {
    __shared__ int s[256];
    int i = blockIdx.x * 256 + threadIdx.x;
    int v = (i < NN) ? deg[i] : 0;
    s[threadIdx.x] = v;
    __syncthreads();
    for (int off = 1; off < 256; off <<= 1) {
        int t = (threadIdx.x >= off) ? s[threadIdx.x - off] : 0;
        __syncthreads();
        s[threadIdx.x] += t;
        __syncthreads();
    }
    if (i < NN) tmp[i] = s[threadIdx.x];
    if (threadIdx.x == 255) bsum[blockIdx.x] = s[255];
}

__global__ __launch_bounds__(512) void scan2_kernel(const int* __restrict__ bsum,
                                                    int* __restrict__ boff) {
    __shared__ int s[512];
    int t = threadIdx.x;
    int v = (t < NB) ? bsum[t] : 0;
    s[t] = v;
    __syncthreads();
    for (int off = 1; off < 512; off <<= 1) {
        int u = (t >= off) ? s[t - off] : 0;
        __syncthreads();
        s[t] += u;
        __syncthreads();
    }
    if (t < NB) boff[t] = s[t] - v;
}

__global__ __launch_bounds__(256) void scan3_kernel(const int* __restrict__ deg,
                                                    const int* __restrict__ tmp,
                                                    const int* __restrict__ boff,
                                                    int* __restrict__ row_ptr,
                                                    float* __restrict__ dinv) {
    int i = blockIdx.x * 256 + threadIdx.x;
    if (i >= NN) return;
    int d = deg[i];
    int start = tmp[i] - d + boff[blockIdx.x];
    row_ptr[i] = start;
    dinv[i] = (d > 0) ? rsqrtf((float)d) : 0.f;
    if (i == NN - 1) row_ptr[NN] = start + d;
}

__global__ __launch_bounds__(256) void fill_kernel(const int* __restrict__ ei,
                                                   const int* __restrict__ row_ptr,
                                                   const int* __restrict__ ppos,
                                                   const float* __restrict__ dinv,
                                                   int2* __restrict__ csr) {
    int e = blockIdx.x * 256 + threadIdx.x;
    if (e >= NE) return;
    int r = ei[e];
    int c = ei[NE + e];
    csr[row_ptr[r] + ppos[e]] = make_int2(c, (int)__float_as_uint(dinv[c]));
}

// Build WT[layer][cout][k] bf16, k = kb*64 + cin, from W[kb][cin][cout] f32.
__global__ __launch_bounds__(256) void wcat_kernel(const float* __restrict__ W1,
                                                   const float* __restrict__ W2,
                                                   const float* __restrict__ W3,
                                                   u16* __restrict__ WT) {
    int idx = blockIdx.x * 256 + threadIdx.x;  // 3 * 64 * 384
    if (idx >= 3 * 64 * 384) return;
    int l = idx / (64 * 384);
    int rem = idx - l * (64 * 384);
    int co = rem / 384;
    int kk = rem - co * 384;  // kb*64 + ci
    const float* W = (l == 0) ? W1 : ((l == 1) ? W2 : W3);
    WT[idx] = f2bf(W[kk * 64 + co]);
}

__global__ __launch_bounds__(256) void cvt_kernel(const float4* __restrict__ in,
                                                  ushort4* __restrict__ outb, int n4) {
    int i = blockIdx.x * 256 + threadIdx.x;
    if (i < n4) {
        float4 v = in[i];
        ushort4 u;
        u.x = f2bf(v.x); u.y = f2bf(v.y); u.z = f2bf(v.z); u.w = f2bf(v.w);
        outb[i] = u;
    }
}

// Lean propagate: t2 = P(t1) (FIRST) or 2*P(t1) - t0.  One wave = 4 nodes.
// QUAD-EDGE gather: quarter q (lanes 16q..16q+15) processes edge k+q; each
// lane loads 8B = 4 bf16 channels, so ONE load instruction fetches FOUR t1
// rows. Epilogue: cross-quarter __shfl_xor(16/32) reduce; q==0 lanes store.
template <bool FIRST>
__global__ __launch_bounds__(256, 6) void prop_kernel(
    const u16* __restrict__ t0, const u16* __restrict__ t1, u16* __restrict__ t2,
    const int2* __restrict__ csr, const int* __restrict__ row_ptr,
    const float* __restrict__ dinv) {
    int lane = threadIdx.x & 63;
    int wid = __builtin_amdgcn_readfirstlane((int)(threadIdx.x >> 6));
    int base = (blockIdx.x * 4 + wid) * 4;
    int q = lane >> 4;   // quarter: edge offset within quad
    int c4 = lane & 15;  // channel group: channels 4*c4 .. 4*c4+3

    int sN[4], dN[4];
    int2 ce[4];
#pragma unroll
    for (int n = 0; n < 4; ++n) {
        int i = base + n;
        sN[n] = row_ptr[i];
        dN[n] = row_ptr[i + 1] - sN[n];
        ce[n] = make_int2(0, 0);
        if (dN[n] > 0) ce[n] = csr[sN[n] + min(lane, dN[n] - 1)];
    }

    float dv[4];
    uint2 x0u[4];
#pragma unroll
    for (int n = 0; n < 4; ++n) {
        dv[n] = dinv[base + n];
        x0u[n] = make_uint2(0u, 0u);
        if (!FIRST) x0u[n] = *(const uint2*)(t0 + (size_t)(base + n) * 64 + c4 * 4);
    }

    int kmax = max(max(min(dN[0], 64), min(dN[1], 64)),
                   max(min(dN[2], 64), min(dN[3], 64)));  // wave-uniform

    float acc[4][4] = {{0.f}};
#pragma unroll 2
    for (int k = 0; k < kmax; k += 4) {
#pragma unroll
        for (int n = 0; n < 4; ++n) {
            int c0 = __builtin_amdgcn_readlane(ce[n].x, k);
            int c1 = __builtin_amdgcn_readlane(ce[n].x, k + 1);
            int c2 = __builtin_amdgcn_readlane(ce[n].x, k + 2);
            int c3 = __builtin_amdgcn_readlane(ce[n].x, k + 3);
            float w0 = __uint_as_float((u32)__builtin_amdgcn_readlane(ce[n].y, k));
            float w1 = __uint_as_float((u32)__builtin_amdgcn_readlane(ce[n].y, k + 1));
            float w2 = __uint_as_float((u32)__builtin_amdgcn_readlane(ce[n].y, k + 2));
            float w3 = __uint_as_float((u32)__builtin_amdgcn_readlane(ce[n].y, k + 3));
            int col = (q & 2) ? ((q & 1) ? c3 : c2) : ((q & 1) ? c1 : c0);
            float w = (q & 2) ? ((q & 1) ? w3 : w2) : ((q & 1) ? w1 : w0);
            w = ((k + q) < dN[n]) ? w : 0.f;
            uint2 v = *(const uint2*)(t1 + (size_t)col * 64 + c4 * 4);
            acc[n][0] = fmaf(w, bflo(v.x), acc[n][0]);
            acc[n][1] = fmaf(w, bfhi(v.x), acc[n][1]);
            acc[n][2] = fmaf(w, bflo(v.y), acc[n][2]);
            acc[n][3] = fmaf(w, bfhi(v.y), acc[n][3]);
        }
    }

    // rare tail: degree > 64 (Poisson(12) -> essentially never)
#pragma unroll
    for (int n = 0; n < 4; ++n) {
        for (int b = 64; b < dN[n]; b += 64) {
            int rem = min(dN[n] - b, 64);
            int2 c2e = csr[sN[n] + b + min(lane, rem - 1)];
            for (int k = 0; k < rem; k += 4) {
                int cc[4];
                float ww[4];
#pragma unroll
                for (int j = 0; j < 4; ++j) {
                    int idx = min(k + j, 63);
                    cc[j] = __builtin_amdgcn_readlane(c2e.x, idx);
                    ww[j] = __uint_as_float((u32)__builtin_amdgcn_readlane(c2e.y, idx));
                }
                int col = (q & 2) ? ((q & 1) ? cc[3] : cc[2]) : ((q & 1) ? cc[1] : cc[0]);
                float w = (q & 2) ? ((q & 1) ? ww[3] : ww[2]) : ((q & 1) ? ww[1] : ww[0]);
                w = ((k + q) < rem) ? w : 0.f;
                uint2 v = *(const uint2*)(t1 + (size_t)col * 64 + c4 * 4);
                acc[n][0] = fmaf(w, bflo(v.x), acc[n][0]);
                acc[n][1] = fmaf(w, bfhi(v.x), acc[n][1]);
                acc[n][2] = fmaf(w, bflo(v.y), acc[n][2]);
                acc[n][3] = fmaf(w, bfhi(v.y), acc[n][3]);
            }
        }
    }

#pragma unroll
    for (int n = 0; n < 4; ++n) {
        float s[4];
#pragma unroll
        for (int j = 0; j < 4; ++j) {
            float a = acc[n][j];
            a += __shfl_xor(a, 16);
            a += __shfl_xor(a, 32);
            s[j] = -dv[n] * a;
        }
        float v0, v1, v2, v3;
        if (FIRST) {
            v0 = s[0]; v1 = s[1]; v2 = s[2]; v3 = s[3];
        } else {
            v0 = fmaf(2.f, s[0], -bflo(x0u[n].x));
            v1 = fmaf(2.f, s[1], -bfhi(x0u[n].x));
            v2 = fmaf(2.f, s[2], -bflo(x0u[n].y));
            v3 = fmaf(2.f, s[3], -bfhi(x0u[n].y));
        }
        if (q == 0) {
            uint2 o;
            o.x = (u32)f2bf(v0) | ((u32)f2bf(v1) << 16);
            o.y = (u32)f2bf(v2) | ((u32)f2bf(v3) << 16);
            *(uint2*)(t2 + (size_t)(base + n) * 64 + c4 * 4) = o;
        }
    }
}

// MFMA GEMM: O[100000x64] = concat(T0..T5)[100000x384] @ Wcat[384x64] + bias.
// WT staged in LDS once per block (padded stride -> ~2-way conflicts max);
// one wave = 32 rows (2 tiles of 16) sharing B-fragments: per kb-step
// 4 global A loads + 8 LDS B reads + 16 MFMA.
// C/D: col=lane&15, row=4*(lane>>4)+reg [verified m89 mapping].
// MODE 0: xout = bf16(relu(O));  MODE 1: fout = relu(O) + pos.
template <int MODE>
__global__ __launch_bounds__(256) void gemm_kernel(
    const u16* __restrict__ T0, const u16* __restrict__ T1, const u16* __restrict__ T2,
    const u16* __restrict__ T3, const u16* __restrict__ T4, const u16* __restrict__ T5,
    const u16* __restrict__ WT, const float* __restrict__ bias,
    u16* __restrict__ xout, float* __restrict__ fout, const float* __restrict__ pos) {
    __shared__ u16 Wl[64 * WSTRIDE];  // 50176 B
    for (int i = threadIdx.x; i < 64 * 192; i += 256) {
        int co = i / 192;
        int k2 = i - co * 192;
        *(u32*)(&Wl[co * WSTRIDE + k2 * 2]) = *(const u32*)(WT + co * 384 + k2 * 2);
    }
    __syncthreads();

    int lane = threadIdx.x & 63;
    int wid = __builtin_amdgcn_readfirstlane((int)(threadIdx.x >> 6));
    int st = blockIdx.x * 4 + wid;  // supertile: 32 rows
    if (st >= NT2) return;
    int r = lane & 15;
    int kg = lane >> 4;
    int rowA = st * 32 + r;
    int rowB = st * 32 + 16 + r;

    f32x4 accA[4], accB[4];
#pragma unroll
    for (int t = 0; t < 4; ++t) {
        float b = bias[t * 16 + r];
        accA[t] = (f32x4){b, b, b, b};
        accB[t] = (f32x4){b, b, b, b};
    }

    const u16* Ts[6] = {T0, T1, T2, T3, T4, T5};
#pragma unroll
    for (int kb = 0; kb < 6; ++kb) {
        const u16* Tb = Ts[kb];
        short8 a0 = *(const short8*)(Tb + (size_t)rowA * 64 + kg * 8);
        short8 a1 = *(const short8*)(Tb + (size_t)rowA * 64 + 32 + kg * 8);
        short8 a2 = *(const short8*)(Tb + (size_t)rowB * 64 + kg * 8);
        short8 a3 = *(const short8*)(Tb + (size_t)rowB * 64 + 32 + kg * 8);
#pragma unroll
        for (int t = 0; t < 4; ++t) {
            const u16* wb = &Wl[(t * 16 + r) * WSTRIDE + kb * 64 + kg * 8];
            short8 b0 = *(const short8*)(wb);
            short8 b1 = *(const short8*)(wb + 32);
            accA[t] = __builtin_amdgcn_mfma_f32_16x16x32_bf16(a0, b0, accA[t], 0, 0, 0);
            accA[t] = __builtin_amdgcn_mfma_f32_16x16x32_bf16(a1, b1, accA[t], 0, 0, 0);
            accB[t] = __builtin_amdgcn_mfma_f32_16x16x32_bf16(a2, b0, accB[t], 0, 0, 0);
            accB[t] = __builtin_amdgcn_mfma_f32_16x16x32_bf16(a3, b1, accB[t], 0, 0, 0);
        }
    }

#pragma unroll
    for (int t = 0; t < 4; ++t) {
#pragma unroll
        for (int rr = 0; rr < 4; ++rr) {
            int col = t * 16 + r;
            int row0 = st * 32 + kg * 4 + rr;
            int row1 = row0 + 16;
            float vA = accA[t][rr];
            float vB = accB[t][rr];
            if (MODE == 0) {
                xout[(size_t)row0 * 64 + col] = f2bf(fmaxf(vA, 0.f));
                xout[(size_t)row1 * 64 + col] = f2bf(fmaxf(vB, 0.f));
            } else {
                fout[(size_t)row0 * 64 + col] = fmaxf(vA, 0.f) + pos[(size_t)row0 * 64 + col];
                fout[(size_t)row1 * 64 + col] = fmaxf(vB, 0.f) + pos[(size_t)row1 * 64 + col];
            }
        }
    }
}

extern "C" void kernel_launch(void* const* d_in, const int* in_sizes, int n_in,
                              void* d_out, int out_size, void* d_ws, size_t ws_size,
                              hipStream_t stream) {
    const float* pos = (const float*)d_in[0];
    const int* ei = (const int*)d_in[1];
    const float* W1 = (const float*)d_in[2];
    const float* b1 = (const float*)d_in[3];
    const float* W2 = (const float*)d_in[4];
    const float* b2 = (const float*)d_in[5];
    const float* W3 = (const float*)d_in[6];
    const float* b3 = (const float*)d_in[7];
    float* out = (float*)d_out;

    char* ws = (char*)d_ws;
    size_t off = 0;
    auto alloc = [&](size_t bytes) {
        void* p = ws + off;
        off += (bytes + 1023) & ~(size_t)1023;
        return p;
    };
    int* deg = (int*)alloc(NN * 4);
    float* dinv = (float*)alloc(NN * 4);
    int* row_ptr = (int*)alloc((NN + 1) * 4);
    int* tmp = (int*)alloc(NN * 4);
    int* bsum = (int*)alloc(NB * 4);
    int* boff = (int*)alloc(NB * 4);
    int* ppos = (int*)alloc((size_t)NE * 4);
    int2* csr = (int2*)alloc((size_t)NE * 8);
    u16* WT = (u16*)alloc((size_t)3 * 64 * 384 * 2);
    u16* X = (u16*)alloc((size_t)NN * NC * 2);
    u16* T1 = (u16*)alloc((size_t)NN * NC * 2);
    u16* T2 = (u16*)alloc((size_t)NN * NC * 2);
    u16* T3 = (u16*)alloc((size_t)NN * NC * 2);
    u16* T4 = (u16*)alloc((size_t)NN * NC * 2);
    u16* T5 = (u16*)alloc((size_t)NN * NC * 2);

    hipMemsetAsync(deg, 0, NN * 4, stream);
    deg_kernel<<<(NE + 255) / 256, 256, 0, stream>>>(ei, deg, ppos);
    scan1_kernel<<<NB, 256, 0, stream>>>(deg, tmp, bsum);
    scan2_kernel<<<1, 512, 0, stream>>>(bsum, boff);
    scan3_kernel<<<NB, 256, 0, stream>>>(deg, tmp, boff, row_ptr, dinv);
    fill_kernel<<<(NE + 255) / 256, 256, 0, stream>>>(ei, row_ptr, ppos, dinv, csr);
    wcat_kernel<<<(3 * 64 * 384 + 255) / 256, 256, 0, stream>>>(W1, W2, W3, WT);

    const int G = NN / 16;               // 6250 blocks: 4 waves x 4 nodes
    const int G4 = (NN * NC / 4) / 256;  // 6250
    const int GG = (NT2 + 3) / 4;        // 782 blocks: 4 supertiles each

    cvt_kernel<<<G4, 256, 0, stream>>>((const float4*)pos, (ushort4*)X, NN * NC / 4);

    // ---- layer 1 ----
    prop_kernel<true><<<G, 256, 0, stream>>>(X, X, T1, csr, row_ptr, dinv);
    prop_kernel<false><<<G, 256, 0, stream>>>(X, T1, T2, csr, row_ptr, dinv);
    prop_kernel<false><<<G, 256, 0, stream>>>(T1, T2, T3, csr, row_ptr, dinv);
    prop_kernel<false><<<G, 256, 0, stream>>>(T2, T3, T4, csr, row_ptr, dinv);
    prop_kernel<false><<<G, 256, 0, stream>>>(T3, T4, T5, csr, row_ptr, dinv);
    gemm_kernel<0><<<GG, 256, 0, stream>>>(X, T1, T2, T3, T4, T5, WT, b1, X, nullptr, nullptr);

    // ---- layer 2 ----
    prop_kernel<true><<<G, 256, 0, stream>>>(X, X, T1, csr, row_ptr, dinv);
    prop_kernel<false><<<G, 256, 0, stream>>>(X, T1, T2, csr, row_ptr, dinv);
    prop_kernel<false><<<G, 256, 0, stream>>>(T1, T2, T3, csr, row_ptr, dinv);
    prop_kernel<false><<<G, 256, 0, stream>>>(T2, T3, T4, csr, row_ptr, dinv);
    prop_kernel<false><<<G, 256, 0, stream>>>(T3, T4, T5, csr, row_ptr, dinv);
    gemm_kernel<0><<<GG, 256, 0, stream>>>(X, T1, T2, T3, T4, T5, WT + 24576, b2, X, nullptr, nullptr);

    // ---- layer 3 ----
    prop_kernel<true><<<G, 256, 0, stream>>>(X, X, T1, csr, row_ptr, dinv);
    prop_kernel<false><<<G, 256, 0, stream>>>(X, T1, T2, csr, row_ptr, dinv);
    prop_kernel<false><<<G, 256, 0, stream>>>(T1, T2, T3, csr, row_ptr, dinv);
    prop_kernel<false><<<G, 256, 0, stream>>>(T2, T3, T4, csr, row_ptr, dinv);
    prop_kernel<false><<<G, 256, 0, stream>>>(T3, T4, T5, csr, row_ptr, dinv);
    gemm_kernel<1><<<GG, 256, 0, stream>>>(X, T1, T2, T3, T4, T5, WT + 2 * 24576, b3, nullptr, out, pos);
}